// Round 4
// baseline (833.889 us; speedup 1.0000x reference)
//
#include <hip/hip_runtime.h>
#include <math.h>

#define L_SEQ 2048
#define DIM   3072
#define NH    24
#define HD    128
#define RANK  16
#define N_QKV 9216
#define KE    3136   // DIM + 16 (T_hi|Up) + 16 (T_lo|Up) + 32 zero pad; 64 | KE

typedef __attribute__((ext_vector_type(8))) short bf16x8;
typedef __attribute__((ext_vector_type(4))) float f32x4;
typedef unsigned short u16;
typedef unsigned int u32;

__device__ __forceinline__ u16 f2bf(float f) {
    union { float f; u32 u; } v; v.f = f;
    return (u16)((v.u + 0x7fffu + ((v.u >> 16) & 1u)) >> 16);
}
__device__ __forceinline__ float bf2f(u16 h) {
    union { u32 u; float f; } v; v.u = ((u32)h) << 16; return v.f;
}

#define GLOBAL_TO_LDS16(gp, lp) \
  __builtin_amdgcn_global_load_lds((const __attribute__((address_space(1))) u32*)(gp), \
                                   (__attribute__((address_space(3))) u32*)(lp), 16, 0, 0)

// ---------------------------------------------------------------------------
// pe [1,1,L,64,2,2] -> pe2 [L][64] (cos, sin)
// ---------------------------------------------------------------------------
__global__ __launch_bounds__(64) void pack_pe_kernel(
    const float* __restrict__ pe, float2* __restrict__ pe2)
{
    int l = blockIdx.x, i = threadIdx.x;
    int base = l * 256 + i * 4;
    float2 cs; cs.x = pe[base]; cs.y = pe[base + 2];
    pe2[l * 64 + i] = cs;
}

// ---------------------------------------------------------------------------
// T[l][r] = dot(X[l,:DIM], W[r,:DIM])  rank-16 LoRA down (fp32 X)
// ---------------------------------------------------------------------------
__global__ __launch_bounds__(256) void lora_down_kernel(
    const float* __restrict__ X, const float* __restrict__ W, float* __restrict__ T)
{
    int l = blockIdx.x;
    int r = threadIdx.x >> 4;
    int lane = threadIdx.x & 15;
    const float* xr = X + (size_t)l * DIM;
    const float* wr = W + (size_t)r * DIM;
    float s = 0.f;
    for (int k = lane; k < DIM; k += 16) s = fmaf(xr[k], wr[k], s);
    #pragma unroll
    for (int mm = 8; mm; mm >>= 1) s += __shfl_xor(s, mm);
    if (lane == 0) T[l * RANK + r] = s;
}

// bf16-X variant with row pitch (for o_ext)
__global__ __launch_bounds__(256) void lora_down_bf_kernel(
    const u16* __restrict__ X, const float* __restrict__ W, float* __restrict__ T, int pitch)
{
    int l = blockIdx.x;
    int r = threadIdx.x >> 4;
    int lane = threadIdx.x & 15;
    const u16* xr = X + (size_t)l * pitch;
    const float* wr = W + (size_t)r * DIM;
    float s = 0.f;
    for (int k = lane; k < DIM; k += 16) s = fmaf(bf2f(xr[k]), wr[k], s);
    #pragma unroll
    for (int mm = 8; mm; mm >>= 1) s += __shfl_xor(s, mm);
    if (lane == 0) T[l * RANK + r] = s;
}

// ---------------------------------------------------------------------------
// pack weights: [0:DIM)=bf16(W), [DIM,DIM+16)=Up, [DIM+16,DIM+32)=Up, pad=0
// ---------------------------------------------------------------------------
__global__ __launch_bounds__(256) void pack_w_kernel(
    const float* __restrict__ W, const float* __restrict__ Up, u16* __restrict__ out)
{
    int row = blockIdx.x;
    const float* wr = W + (size_t)row * DIM;
    u16* orow = out + (size_t)row * KE;
    #pragma unroll
    for (int it = 0; it < 3; it++) {
        int c4 = threadIdx.x + it * 256;
        float4 v = ((const float4*)wr)[c4];
        ushort4 o = {f2bf(v.x), f2bf(v.y), f2bf(v.z), f2bf(v.w)};
        *(ushort4*)(orow + c4 * 4) = o;
    }
    int t = threadIdx.x;
    if (t < RANK) {
        u16 b = f2bf(Up[row * RANK + t]);
        orow[DIM + t] = b;
        orow[DIM + RANK + t] = b;
    } else if (t >= 32 && t < 64) {
        orow[DIM + t] = 0;
    }
}

// pack activations: [0:DIM)=bf16(X), then T hi/lo, pad=0
__global__ __launch_bounds__(256) void pack_x_kernel(
    const float* __restrict__ X, const float* __restrict__ T, u16* __restrict__ out)
{
    int row = blockIdx.x;
    const float* xr = X + (size_t)row * DIM;
    u16* orow = out + (size_t)row * KE;
    #pragma unroll
    for (int it = 0; it < 3; it++) {
        int c4 = threadIdx.x + it * 256;
        float4 v = ((const float4*)xr)[c4];
        ushort4 o = {f2bf(v.x), f2bf(v.y), f2bf(v.z), f2bf(v.w)};
        *(ushort4*)(orow + c4 * 4) = o;
    }
    int t = threadIdx.x;
    if (t < RANK) {
        float tv = T[row * RANK + t];
        u16 hi = f2bf(tv);
        orow[DIM + t] = hi;
        orow[DIM + RANK + t] = f2bf(tv - bf2f(hi));
    } else if (t >= 32 && t < 64) {
        orow[DIM + t] = 0;
    }
}

// write T hi/lo + zero pad into existing bf16 [row][KE] buffer (o_ext)
__global__ __launch_bounds__(64) void pack_t_kernel(
    const float* __restrict__ T, u16* __restrict__ out)
{
    int row = blockIdx.x, t = threadIdx.x;
    u16* orow = out + (size_t)row * KE;
    if (t < RANK) {
        float tv = T[row * RANK + t];
        u16 hi = f2bf(tv);
        orow[DIM + t] = hi;
        orow[DIM + RANK + t] = f2bf(tv - bf2f(hi));
    } else if (t >= 32) {
        orow[DIM + t] = 0;
    }
}

// ---------------------------------------------------------------------------
// bf16 MFMA GEMM, 256x256 tile, BK=64, 8 waves (2M x 4N), double-buffered
// 128 KB LDS, LoRA folded into K. 256-tile halves L2/L3 staging traffic vs
// 128-tile (each W/A panel re-read half as often) and keeps 64 KB/CU of
// global_load_lds in flight. K-loop = verified minimum 2-phase pipeline:
// issue next-tile global_load_lds FIRST, then ds_read+MFMA current tile,
// then one vmcnt(0)+s_barrier (raw barrier; no drain before compute).
// Grid is XCD-swizzled (bid&7 = XCD, nwg%8==0 -> bijective).
// MODE 0: C = A@W^T + bias -> fp32 [M][N]  (proj)
// MODE 1: qkv with fused RMSNorm+RoPE epilogue (q,k bf16 [2][NH][L][HD];
//   v bf16 [NH][HD][L] swizzled). Each 256-col tile = exactly 2 heads.
// ---------------------------------------------------------------------------
template<int MODE>
__global__ __launch_bounds__(512) void gemm_mfma_kernel(
    const u16* __restrict__ A, const u16* __restrict__ W,
    const float* __restrict__ bias,
    float* __restrict__ Cf,
    u16* __restrict__ qkbf, u16* __restrict__ vT,
    const float2* __restrict__ pe2,
    const float* __restrict__ q_scale, const float* __restrict__ k_scale,
    int M, int N, int K)
{
    __shared__ __align__(16) u16 a_s[2][256 * 64];   // 64 KB (dbuf)
    __shared__ __align__(16) u16 b_s[2][256 * 64];   // 64 KB (dbuf)

    int tid = threadIdx.x;
    int wave = tid >> 6, lane = tid & 63;
    int quad = lane >> 4, l15 = lane & 15;
    int wm = wave >> 2, wn = wave & 3;               // 2M x 4N wave grid

    // XCD swizzle: nwg % 8 == 0 for both modes (288 / 96); m-inner order.
    int num_m = M >> 8, num_n = N >> 8;
    int swz = (blockIdx.x & 7) * ((num_m * num_n) >> 3) + (blockIdx.x >> 3);
    int bm = (swz % num_m) << 8;
    int bn = (swz / num_m) << 8;

    // staging: 4 issues per matrix; 64 rows x 128 B per issue; chunk XOR swizzle
    const u16* ga[4]; const u16* gb[4];
    u16 *lA[4], *lB[4];
    #pragma unroll
    for (int e = 0; e < 4; e++) {
        int r = e * 64 + (tid >> 3);
        int g = (tid & 7) ^ (r & 7);
        ga[e] = A + (size_t)(bm + r) * K + g * 8;
        gb[e] = W + (size_t)(bn + r) * K + g * 8;
        lA[e] = &a_s[0][(e * 64 + wave * 8) * 64];
        lB[e] = &b_s[0][(e * 64 + wave * 8) * 64];
    }

    f32x4 acc[8][4];
    #pragma unroll
    for (int i = 0; i < 8; i++)
        #pragma unroll
        for (int j = 0; j < 4; j++) acc[i][j] = (f32x4){0.f, 0.f, 0.f, 0.f};

    int abase[8], bbase[4], co[2];
    #pragma unroll
    for (int i = 0; i < 8; i++) abase[i] = (wm * 128 + i * 16 + l15) * 64;
    #pragma unroll
    for (int j = 0; j < 4; j++) bbase[j] = (wn * 64 + j * 16 + l15) * 64;
    #pragma unroll
    for (int ks = 0; ks < 2; ks++) co[ks] = ((ks * 4 + quad) ^ (l15 & 7)) * 8;

    // prologue: stage tile 0 into buffer 0, drain, rendezvous
    #pragma unroll
    for (int e = 0; e < 4; e++) {
        GLOBAL_TO_LDS16(ga[e], lA[e]);
        GLOBAL_TO_LDS16(gb[e], lB[e]);
    }
    asm volatile("s_waitcnt vmcnt(0)" ::: "memory");
    __builtin_amdgcn_s_barrier();

    int nt = K >> 6;
    for (int t = 0; t < nt; ++t) {
        int cur = t & 1;
        int cb = cur * 16384;
        int nb = (cur ^ 1) * 16384;
        if (t + 1 < nt) {
            // issue tile t+1 into the other buffer BEFORE computing tile t;
            // its latency hides under the MFMA phase below
            int ko = (t + 1) << 6;
            #pragma unroll
            for (int e = 0; e < 4; e++) {
                GLOBAL_TO_LDS16(ga[e] + ko, lA[e] + nb);
                GLOBAL_TO_LDS16(gb[e] + ko, lB[e] + nb);
            }
        }
        __builtin_amdgcn_s_setprio(1);
        #pragma unroll
        for (int ks = 0; ks < 2; ks++) {
            bf16x8 af[8], bf[4];
            #pragma unroll
            for (int i = 0; i < 8; i++) af[i] = *(const bf16x8*)&a_s[0][cb + abase[i] + co[ks]];
            #pragma unroll
            for (int j = 0; j < 4; j++) bf[j] = *(const bf16x8*)&b_s[0][cb + bbase[j] + co[ks]];
            #pragma unroll
            for (int i = 0; i < 8; i++)
                #pragma unroll
                for (int j = 0; j < 4; j++)
                    acc[i][j] = __builtin_amdgcn_mfma_f32_16x16x32_bf16(af[i], bf[j], acc[i][j], 0, 0, 0);
        }
        __builtin_amdgcn_s_setprio(0);
        // one barrier per tile: every wave's ds_reads of buf[cur] completed
        // (compiler lgkmcnt) and tile t+1 fully staged (vmcnt 0) before any
        // wave proceeds to overwrite buf[cur] at t+1.
        asm volatile("s_waitcnt vmcnt(0)" ::: "memory");
        __builtin_amdgcn_s_barrier();
    }

    if (MODE == 0) {
        #pragma unroll
        for (int j = 0; j < 4; j++) {
            int col = bn + wn * 64 + j * 16 + l15;
            float bj = bias[col];
            #pragma unroll
            for (int i = 0; i < 8; i++)
                #pragma unroll
                for (int r = 0; r < 4; r++) {
                    int row = bm + wm * 128 + i * 16 + quad * 4 + r;
                    Cf[(size_t)row * N + col] = acc[i][j][r] + bj;
                }
        }
        return;
    }

    // ---- MODE 1: fused qkv epilogue (256-col tile = 2 heads) ----
    int mq = (bn >= 2 * DIM) ? 2 : (bn >= DIM ? 1 : 0);
    int h0 = (bn - mq * DIM) >> 7;        // even; first of the 2 heads
    int h = h0 + (wn >> 1);               // this wave's head
    int d = (wn & 1) * 64;                // wave's base d within the head

    #pragma unroll
    for (int j = 0; j < 4; j++) {
        float bj = bias[bn + wn * 64 + j * 16 + l15];
        #pragma unroll
        for (int i = 0; i < 8; i++)
            #pragma unroll
            for (int r = 0; r < 4; r++) acc[i][j][r] += bj;
    }

    if (mq == 2) {
        // V: store transposed [h][d][L] with chunk swizzle baked in
        #pragma unroll
        for (int j = 0; j < 4; j++) {
            int dd = d + j * 16 + l15;
            u16* vrow = vT + ((size_t)h * HD + dd) * L_SEQ;
            #pragma unroll
            for (int i = 0; i < 8; i++)
                #pragma unroll
                for (int r = 0; r < 4; r++) {
                    int kv = bm + wm * 128 + i * 16 + quad * 4 + r;
                    int slot = ((kv >> 3) & 7) ^ (dd & 7);
                    int colp = (kv & ~63) + slot * 8 + (kv & 7);
                    vrow[colp] = f2bf(acc[i][j][r]);
                }
        }
    } else {
        // per-row sum of squares over this wave's 64 cols; reduce across the
        // wave pair (wn&~1, wn|1) covering the head's 128 cols via LDS.
        float ssp[8][4];
        #pragma unroll
        for (int i = 0; i < 8; i++)
            #pragma unroll
            for (int r = 0; r < 4; r++) {
                float s = 0.f;
                #pragma unroll
                for (int j = 0; j < 4; j++) s = fmaf(acc[i][j][r], acc[i][j][r], s);
                #pragma unroll
                for (int mm = 8; mm; mm >>= 1) s += __shfl_xor(s, mm);
                ssp[i][r] = s;
            }
        float* ss_s = (float*)a_s;   // 4 KB scratch; K-loop done (barriered)
        if (l15 == 0) {
            #pragma unroll
            for (int i = 0; i < 8; i++)
                *(float4*)&ss_s[wn * 256 + wm * 128 + i * 16 + quad * 4] =
                    make_float4(ssp[i][0], ssp[i][1], ssp[i][2], ssp[i][3]);
        }
        __syncthreads();
        float rfac[8][4];
        #pragma unroll
        for (int i = 0; i < 8; i++) {
            int base = wm * 128 + i * 16 + quad * 4;
            float4 s0 = *(const float4*)&ss_s[(wn & ~1) * 256 + base];
            float4 s1 = *(const float4*)&ss_s[(wn | 1) * 256 + base];
            rfac[i][0] = rsqrtf((s0.x + s1.x) * (1.f / HD) + 1e-6f);
            rfac[i][1] = rsqrtf((s0.y + s1.y) * (1.f / HD) + 1e-6f);
            rfac[i][2] = rsqrtf((s0.z + s1.z) * (1.f / HD) + 1e-6f);
            rfac[i][3] = rsqrtf((s0.w + s1.w) * (1.f / HD) + 1e-6f);
        }
        const float* scale = mq ? k_scale : q_scale;
        float sgn = (l15 & 1) ? 1.f : -1.f;
        u16* obase = qkbf + (size_t)(mq * NH + h) * L_SEQ * HD;
        #pragma unroll
        for (int j = 0; j < 4; j++) {
            int dd = d + j * 16 + l15;
            float sd = scale[dd];
            #pragma unroll
            for (int i = 0; i < 8; i++)
                #pragma unroll
                for (int r = 0; r < 4; r++) {
                    int row = bm + wm * 128 + i * 16 + quad * 4 + r;
                    float t = acc[i][j][r] * rfac[i][r] * sd;
                    float tp = __shfl_xor(t, 1);
                    float2 cs = pe2[row * 64 + (dd >> 1)];
                    float o = fmaf(cs.x, t, sgn * cs.y * tp);
                    obase[(size_t)row * HD + dd] = f2bf(o);
                }
        }
    }
}

// ---------------------------------------------------------------------------
// bf16 MFMA flash attention, FIXED-max softmax (M = 64 log2-units; safe since
// RMSNorm bounds |q|=|k|=sqrt(128) -> |s|*sc <= 16.4 log2; fp is scale-free so
// the offset costs no precision). No online rescale, no per-iter shfls.
// XCD-grouped dispatch: bid&7 = XCD owns 3 heads (KV L2-resident).
// ---------------------------------------------------------------------------
__global__ __launch_bounds__(256) void attn_mfma_kernel(
    const u16* __restrict__ qk_bf, const u16* __restrict__ vT, u16* __restrict__ Og)
{
    __shared__ __align__(16) u16 k_s[64 * 128];    // 16 KB, [kv][d] 16-chunk swizzled
    __shared__ __align__(16) u16 v_s[128 * 64];    // 16 KB, [d][kv] 8-chunk swizzled
    __shared__ __align__(16) u16 p_s[4][16 * 72];  // 9 KB per-wave P

    int bid = blockIdx.x;
    int loc = bid >> 3;
    int h = (bid & 7) * 3 + (loc >> 5);
    int q0 = (loc & 31) * 64;
    int tid = threadIdx.x;
    int wave = tid >> 6, lane = tid & 63;
    int quad = lane >> 4, l15 = lane & 15;
    const u16* qb = qk_bf + (size_t)h * L_SEQ * HD;
    const u16* kb = qk_bf + (size_t)(NH + h) * L_SEQ * HD;
    const u16* vTh = vT + (size_t)h * HD * L_SEQ;

    bf16x8 aq[4];
    {
        const u16* qr = qb + (size_t)(q0 + wave * 16 + l15) * HD + quad * 8;
        #pragma unroll
        for (int ks = 0; ks < 4; ks++) aq[ks] = *(const bf16x8*)(qr + ks * 32);
    }

    f32x4 o_acc[8];
    #pragma unroll
    for (int n = 0; n < 8; n++) o_acc[n] = (f32x4){0.f, 0.f, 0.f, 0.f};
    float lsum[4] = {0.f, 0.f, 0.f, 0.f};
    const float sc = 0.08838834764831845f * 1.4426950408889634f;  // /sqrt(128)*log2e
    const float MB = 64.0f;                                       // fixed max, log2 units

    const u16* gk[4];
    #pragma unroll
    for (int e = 0; e < 4; e++) {
        int r = wave * 16 + e * 4 + (lane >> 4);
        int g = l15 ^ (r & 15);
        gk[e] = kb + (size_t)r * HD + g * 8;
    }
    const u16* gv[4];
    #pragma unroll
    for (int e = 0; e < 4; e++) {
        int d = wave * 32 + e * 8 + (lane >> 3);
        gv[e] = vTh + (size_t)d * L_SEQ + (lane & 7) * 8;
    }
    int vco[2];
    #pragma unroll
    for (int ks = 0; ks < 2; ks++) vco[ks] = ((ks * 4 + quad) ^ (l15 & 7)) * 8;

    for (int kv0 = 0; kv0 < L_SEQ; kv0 += 64) {
        __syncthreads();
        #pragma unroll
        for (int e = 0; e < 4; e++) {
            GLOBAL_TO_LDS16(gk[e] + (size_t)kv0 * HD, &k_s[(wave * 16 + e * 4) * 128]);
            GLOBAL_TO_LDS16(gv[e] + kv0, &v_s[(wave * 32 + e * 8) * 64]);
        }
        __syncthreads();

        // S = Q K^T
        f32x4 sacc[4];
        #pragma unroll
        for (int j = 0; j < 4; j++) sacc[j] = (f32x4){0.f, 0.f, 0.f, 0.f};
        #pragma unroll
        for (int ks = 0; ks < 4; ks++) {
            #pragma unroll
            for (int j = 0; j < 4; j++) {
                int n = j * 16 + l15;
                int slot = (ks * 4 + quad) ^ (n & 15);
                bf16x8 bk = *(const bf16x8*)&k_s[n * 128 + slot * 8];
                sacc[j] = __builtin_amdgcn_mfma_f32_16x16x32_bf16(aq[ks], bk, sacc[j], 0, 0, 0);
            }
        }

        // p = exp2(s*sc - MB); accumulate row sums; write P to LDS
        #pragma unroll
        for (int j = 0; j < 4; j++)
            #pragma unroll
            for (int r = 0; r < 4; r++) {
                float p = exp2f(fmaf(sacc[j][r], sc, -MB));
                sacc[j][r] = p;
                lsum[r] += p;
                p_s[wave][(quad * 4 + r) * 72 + j * 16 + l15] = f2bf(p);
            }
        bf16x8 ap[2];
        #pragma unroll
        for (int ks = 0; ks < 2; ks++)
            ap[ks] = *(const bf16x8*)&p_s[wave][l15 * 72 + ks * 32 + quad * 8];

        // O += P V  (no rescale — fixed max)
        #pragma unroll
        for (int ks = 0; ks < 2; ks++) {
            #pragma unroll
            for (int n = 0; n < 8; n++) {
                bf16x8 bv = *(const bf16x8*)&v_s[(n * 16 + l15) * 64 + vco[ks]];
                o_acc[n] = __builtin_amdgcn_mfma_f32_16x16x32_bf16(ap[ks], bv, o_acc[n], 0, 0, 0);
            }
        }
    }

    // single end-of-loop row-sum reduction across the 16-lane groups
    #pragma unroll
    for (int r = 0; r < 4; r++) {
        #pragma unroll
        for (int mm = 8; mm; mm >>= 1) lsum[r] += __shfl_xor(lsum[r], mm);
    }

    #pragma unroll
    for (int r = 0; r < 4; r++) {
        float inv = 1.f / lsum[r];
        int row = q0 + wave * 16 + quad * 4 + r;
        u16* orow = Og + (size_t)row * KE + h * HD;
        #pragma unroll
        for (int n = 0; n < 8; n++)
            orow[n * 16 + l15] = f2bf(o_acc[n][r] * inv);
    }
}

// ---------------------------------------------------------------------------
extern "C" void kernel_launch(void* const* d_in, const int* in_sizes, int n_in,
                              void* d_out, int out_size, void* d_ws, size_t ws_size,
                              hipStream_t stream)
{
    const float* x         = (const float*)d_in[0];
    const float* pe        = (const float*)d_in[1];
    const float* qkv_w     = (const float*)d_in[2];
    const float* qkv_b     = (const float*)d_in[3];
    const float* proj_w    = (const float*)d_in[4];
    const float* proj_b    = (const float*)d_in[5];
    const float* qkv_down  = (const float*)d_in[6];
    const float* qkv_up    = (const float*)d_in[7];
    const float* proj_down = (const float*)d_in[8];
    const float* proj_up   = (const float*)d_in[9];
    const float* q_scale   = (const float*)d_in[10];
    const float* k_scale   = (const float*)d_in[11];
    float* out = (float*)d_out;

    char* w = (char*)d_ws;
    u16*   qk_bf  = (u16*)w;    w += (size_t)2 * NH * L_SEQ * HD * 2;  // 25.2 MB
    u16*   vT_bf  = (u16*)w;    w += (size_t)NH * HD * L_SEQ * 2;      // 12.6 MB
    u16*   x_ext  = (u16*)w;    w += (size_t)L_SEQ * KE * 2;           // 12.8 MB
    u16*   wq_ext = (u16*)w;    w += (size_t)N_QKV * KE * 2;           // 57.8 MB
    u16*   wp_ext = (u16*)w;    w += (size_t)DIM * KE * 2;             // 19.3 MB
    u16*   o_ext  = (u16*)w;    w += (size_t)L_SEQ * KE * 2;           // 12.8 MB
    float2* pe2   = (float2*)w; w += (size_t)L_SEQ * 64 * sizeof(float2);
    float* t1     = (float*)w;  w += (size_t)L_SEQ * RANK * 4;
    float* t2     = (float*)w;

    pack_pe_kernel<<<L_SEQ, 64, 0, stream>>>(pe, pe2);
    pack_w_kernel<<<N_QKV, 256, 0, stream>>>(qkv_w, qkv_up, wq_ext);
    pack_w_kernel<<<DIM, 256, 0, stream>>>(proj_w, proj_up, wp_ext);
    lora_down_kernel<<<L_SEQ, 256, 0, stream>>>(x, qkv_down, t1);
    pack_x_kernel<<<L_SEQ, 256, 0, stream>>>(x, t1, x_ext);

    gemm_mfma_kernel<1><<<(N_QKV / 256) * (L_SEQ / 256), 512, 0, stream>>>(
        x_ext, wq_ext, qkv_b, nullptr, qk_bf, vT_bf, pe2, q_scale, k_scale,
        L_SEQ, N_QKV, KE);
    attn_mfma_kernel<<<(L_SEQ / 64) * NH, 256, 0, stream>>>(qk_bf, vT_bf, o_ext);
    lora_down_bf_kernel<<<L_SEQ, 256, 0, stream>>>(o_ext, proj_down, t2, KE);
    pack_t_kernel<<<L_SEQ, 64, 0, stream>>>(t2, o_ext);
    gemm_mfma_kernel<0><<<(DIM / 256) * (L_SEQ / 256), 512, 0, stream>>>(
        o_ext, wp_ext, proj_b, out, nullptr, nullptr, nullptr, nullptr, nullptr,
        L_SEQ, DIM, KE);
}

// Round 5
// 713.653 us; speedup vs baseline: 1.1685x; 1.1685x over previous
//
#include <hip/hip_runtime.h>
#include <math.h>

#define L_SEQ 2048
#define DIM   3072
#define NH    24
#define HD    128
#define RANK  16
#define N_QKV 9216
#define KE    3136   // DIM + 16 (T_hi|Up) + 16 (T_lo|Up) + 32 zero pad; 64 | KE

typedef __attribute__((ext_vector_type(8))) short bf16x8;
typedef __attribute__((ext_vector_type(4))) float f32x4;
typedef unsigned short u16;
typedef unsigned int u32;

__device__ __forceinline__ u16 f2bf(float f) {
    union { float f; u32 u; } v; v.f = f;
    return (u16)((v.u + 0x7fffu + ((v.u >> 16) & 1u)) >> 16);
}
__device__ __forceinline__ float bf2f(u16 h) {
    union { u32 u; float f; } v; v.u = ((u32)h) << 16; return v.f;
}

#define GLOBAL_TO_LDS16(gp, lp) \
  __builtin_amdgcn_global_load_lds((const __attribute__((address_space(1))) u32*)(gp), \
                                   (__attribute__((address_space(3))) u32*)(lp), 16, 0, 0)

// ---------------------------------------------------------------------------
// pe [1,1,L,64,2,2] -> pe2 [L][64] (cos, sin)
// ---------------------------------------------------------------------------
__global__ __launch_bounds__(64) void pack_pe_kernel(
    const float* __restrict__ pe, float2* __restrict__ pe2)
{
    int l = blockIdx.x, i = threadIdx.x;
    int base = l * 256 + i * 4;
    float2 cs; cs.x = pe[base]; cs.y = pe[base + 2];
    pe2[l * 64 + i] = cs;
}

// ---------------------------------------------------------------------------
// T[l][r] = dot(X[l,:DIM], W[r,:DIM])  rank-16 LoRA down (fp32 X)
// ---------------------------------------------------------------------------
__global__ __launch_bounds__(256) void lora_down_kernel(
    const float* __restrict__ X, const float* __restrict__ W, float* __restrict__ T)
{
    int l = blockIdx.x;
    int r = threadIdx.x >> 4;
    int lane = threadIdx.x & 15;
    const float* xr = X + (size_t)l * DIM;
    const float* wr = W + (size_t)r * DIM;
    float s = 0.f;
    for (int k = lane; k < DIM; k += 16) s = fmaf(xr[k], wr[k], s);
    #pragma unroll
    for (int mm = 8; mm; mm >>= 1) s += __shfl_xor(s, mm);
    if (lane == 0) T[l * RANK + r] = s;
}

// bf16-X variant with row pitch (for o_ext)
__global__ __launch_bounds__(256) void lora_down_bf_kernel(
    const u16* __restrict__ X, const float* __restrict__ W, float* __restrict__ T, int pitch)
{
    int l = blockIdx.x;
    int r = threadIdx.x >> 4;
    int lane = threadIdx.x & 15;
    const u16* xr = X + (size_t)l * pitch;
    const float* wr = W + (size_t)r * DIM;
    float s = 0.f;
    for (int k = lane; k < DIM; k += 16) s = fmaf(bf2f(xr[k]), wr[k], s);
    #pragma unroll
    for (int mm = 8; mm; mm >>= 1) s += __shfl_xor(s, mm);
    if (lane == 0) T[l * RANK + r] = s;
}

// ---------------------------------------------------------------------------
// pack weights: [0:DIM)=bf16(W), [DIM,DIM+16)=Up, [DIM+16,DIM+32)=Up, pad=0
// ---------------------------------------------------------------------------
__global__ __launch_bounds__(256) void pack_w_kernel(
    const float* __restrict__ W, const float* __restrict__ Up, u16* __restrict__ out)
{
    int row = blockIdx.x;
    const float* wr = W + (size_t)row * DIM;
    u16* orow = out + (size_t)row * KE;
    #pragma unroll
    for (int it = 0; it < 3; it++) {
        int c4 = threadIdx.x + it * 256;
        float4 v = ((const float4*)wr)[c4];
        ushort4 o = {f2bf(v.x), f2bf(v.y), f2bf(v.z), f2bf(v.w)};
        *(ushort4*)(orow + c4 * 4) = o;
    }
    int t = threadIdx.x;
    if (t < RANK) {
        u16 b = f2bf(Up[row * RANK + t]);
        orow[DIM + t] = b;
        orow[DIM + RANK + t] = b;
    } else if (t >= 32 && t < 64) {
        orow[DIM + t] = 0;
    }
}

// pack activations: [0:DIM)=bf16(X), then T hi/lo, pad=0
__global__ __launch_bounds__(256) void pack_x_kernel(
    const float* __restrict__ X, const float* __restrict__ T, u16* __restrict__ out)
{
    int row = blockIdx.x;
    const float* xr = X + (size_t)row * DIM;
    u16* orow = out + (size_t)row * KE;
    #pragma unroll
    for (int it = 0; it < 3; it++) {
        int c4 = threadIdx.x + it * 256;
        float4 v = ((const float4*)xr)[c4];
        ushort4 o = {f2bf(v.x), f2bf(v.y), f2bf(v.z), f2bf(v.w)};
        *(ushort4*)(orow + c4 * 4) = o;
    }
    int t = threadIdx.x;
    if (t < RANK) {
        float tv = T[row * RANK + t];
        u16 hi = f2bf(tv);
        orow[DIM + t] = hi;
        orow[DIM + RANK + t] = f2bf(tv - bf2f(hi));
    } else if (t >= 32 && t < 64) {
        orow[DIM + t] = 0;
    }
}

// write T hi/lo + zero pad into existing bf16 [row][KE] buffer (o_ext)
__global__ __launch_bounds__(64) void pack_t_kernel(
    const float* __restrict__ T, u16* __restrict__ out)
{
    int row = blockIdx.x, t = threadIdx.x;
    u16* orow = out + (size_t)row * KE;
    if (t < RANK) {
        float tv = T[row * RANK + t];
        u16 hi = f2bf(tv);
        orow[DIM + t] = hi;
        orow[DIM + RANK + t] = f2bf(tv - bf2f(hi));
    } else if (t >= 32) {
        orow[DIM + t] = 0;
    }
}

// ---------------------------------------------------------------------------
// bf16 MFMA GEMM, 128x128 tile, BK=64, double-buffered LDS (64 KB), LoRA
// folded into K. K-loop is a 2-deep counted-vmcnt pipeline: issue tile t+1's
// 8 global_load_lds, then s_waitcnt vmcnt(8) retires only tile t's loads
// (issued one full iteration earlier -> ~zero exposed latency), barrier,
// compute tile t, barrier. vmcnt never drains to 0 in the main loop.
// 128² tile keeps 1152/384 blocks = fine-grained packing on 256 CUs (the
// 256² variant left 224 CUs idle for half the dispatch - R4 regression).
// Block mapping is XCD-aware (bid&7 = XCD heuristic): each XCD owns a
// 4-mtile x (num_n/2) rectangle; m-inner order keeps its 3.2 MB A slab
// L2-resident while each W n-slab is consumed by 4 co-resident blocks once.
// MODE 0: C = A@W^T + bias -> fp32 [M][N]  (proj)
// MODE 1: qkv with fused RMSNorm+RoPE epilogue (q,k bf16 [2][NH][L][HD];
//   v bf16 [NH][HD][L] swizzled).
// ---------------------------------------------------------------------------
template<int MODE>
__global__ __launch_bounds__(256) void gemm_mfma_kernel(
    const u16* __restrict__ A, const u16* __restrict__ W,
    const float* __restrict__ bias,
    float* __restrict__ Cf,
    u16* __restrict__ qkbf, u16* __restrict__ vT,
    const float2* __restrict__ pe2,
    const float* __restrict__ q_scale, const float* __restrict__ k_scale,
    int M, int N, int K)
{
    __shared__ __align__(16) u16 a_s[2][128 * 64];   // 32 KB (dbuf)
    __shared__ __align__(16) u16 b_s[2][128 * 64];   // 32 KB (dbuf)

    int tid = threadIdx.x;
    int wave = tid >> 6, lane = tid & 63;
    int quad = lane >> 4, l15 = lane & 15;
    int wm = wave >> 1, wn = wave & 1;

    // XCD-aware mapping: num_m must be 16, num_n even.
    int num_n = N >> 7;
    int xcd = blockIdx.x & 7;
    int loc = blockIdx.x >> 3;
    int bm = (((xcd & 3) << 2) + (loc & 3)) << 7;
    int bn = ((xcd >> 2) * (num_n >> 1) + (loc >> 2)) << 7;

    // staging: 4 issues per matrix; 32 rows x 128 B per issue; chunk XOR swizzle
    const u16* ga[4]; const u16* gb[4];
    u16 *lA[4], *lB[4];
    #pragma unroll
    for (int e = 0; e < 4; e++) {
        int r = e * 32 + (tid >> 3);
        int g = (tid & 7) ^ (r & 7);
        ga[e] = A + (size_t)(bm + r) * K + g * 8;
        gb[e] = W + (size_t)(bn + r) * K + g * 8;
        lA[e] = &a_s[0][(e * 32 + wave * 8) * 64];
        lB[e] = &b_s[0][(e * 32 + wave * 8) * 64];
    }

    f32x4 acc[4][4];
    #pragma unroll
    for (int i = 0; i < 4; i++)
        #pragma unroll
        for (int j = 0; j < 4; j++) acc[i][j] = (f32x4){0.f, 0.f, 0.f, 0.f};

    int abase[4], bbase[4], co[2];
    #pragma unroll
    for (int i = 0; i < 4; i++) {
        abase[i] = (wm * 64 + i * 16 + l15) * 64;
        bbase[i] = (wn * 64 + i * 16 + l15) * 64;
    }
    #pragma unroll
    for (int ks = 0; ks < 2; ks++) co[ks] = ((ks * 4 + quad) ^ (l15 & 7)) * 8;

    // prologue: issue tile 0 into buffer 0 (no wait here; iter 0's vmcnt(8)
    // retires these 8 after issuing tile 1)
    #pragma unroll
    for (int e = 0; e < 4; e++) {
        GLOBAL_TO_LDS16(ga[e], lA[e]);
        GLOBAL_TO_LDS16(gb[e], lB[e]);
    }

    int nt = K >> 6;
    for (int t = 0; t < nt; ++t) {
        int cur = t & 1;
        int cb = cur * 8192;
        int nb = (cur ^ 1) * 8192;
        if (t + 1 < nt) {
            // issue tile t+1, then wait only for tile t's 8 loads; the 8
            // newest (t+1) stay in flight across the barrier + compute
            int ko = (t + 1) << 6;
            #pragma unroll
            for (int e = 0; e < 4; e++) {
                GLOBAL_TO_LDS16(ga[e] + ko, lA[e] + nb);
                GLOBAL_TO_LDS16(gb[e] + ko, lB[e] + nb);
            }
            asm volatile("s_waitcnt vmcnt(8)" ::: "memory");
        } else {
            asm volatile("s_waitcnt vmcnt(0)" ::: "memory");
        }
        __builtin_amdgcn_s_barrier();   // all waves' tile-t stages landed
        __builtin_amdgcn_s_setprio(1);
        #pragma unroll
        for (int ks = 0; ks < 2; ks++) {
            bf16x8 af[4], bf[4];
            #pragma unroll
            for (int i = 0; i < 4; i++) af[i] = *(const bf16x8*)&a_s[0][cb + abase[i] + co[ks]];
            #pragma unroll
            for (int j = 0; j < 4; j++) bf[j] = *(const bf16x8*)&b_s[0][cb + bbase[j] + co[ks]];
            #pragma unroll
            for (int i = 0; i < 4; i++)
                #pragma unroll
                for (int j = 0; j < 4; j++)
                    acc[i][j] = __builtin_amdgcn_mfma_f32_16x16x32_bf16(af[i], bf[j], acc[i][j], 0, 0, 0);
        }
        __builtin_amdgcn_s_setprio(0);
        // all waves done reading buf[cur] before t+1 stages tile t+2 into it
        __builtin_amdgcn_s_barrier();
    }

    if (MODE == 0) {
        #pragma unroll
        for (int j = 0; j < 4; j++) {
            int col = bn + wn * 64 + j * 16 + l15;
            float bj = bias[col];
            #pragma unroll
            for (int i = 0; i < 4; i++)
                #pragma unroll
                for (int r = 0; r < 4; r++) {
                    int row = bm + wm * 64 + i * 16 + quad * 4 + r;
                    Cf[(size_t)row * N + col] = acc[i][j][r] + bj;
                }
        }
        return;
    }

    // ---- MODE 1: fused qkv epilogue ----
    int tn = bn >> 7;
    int mq = (tn >= 48) ? 2 : (tn >= 24 ? 1 : 0);
    int h = tn - mq * 24;

    #pragma unroll
    for (int j = 0; j < 4; j++) {
        float bj = bias[bn + wn * 64 + j * 16 + l15];
        #pragma unroll
        for (int i = 0; i < 4; i++)
            #pragma unroll
            for (int r = 0; r < 4; r++) acc[i][j][r] += bj;
    }

    if (mq == 2) {
        // V: store transposed [h][d][L] with chunk swizzle baked in
        #pragma unroll
        for (int j = 0; j < 4; j++) {
            int d = wn * 64 + j * 16 + l15;
            u16* vrow = vT + ((size_t)h * HD + d) * L_SEQ;
            #pragma unroll
            for (int i = 0; i < 4; i++)
                #pragma unroll
                for (int r = 0; r < 4; r++) {
                    int kv = bm + wm * 64 + i * 16 + quad * 4 + r;
                    int slot = ((kv >> 3) & 7) ^ (d & 7);
                    int colp = (kv & ~63) + slot * 8 + (kv & 7);
                    vrow[colp] = f2bf(acc[i][j][r]);
                }
        }
    } else {
        // per-row sum of squares over this wave's 64 cols
        float ssp[4][4];
        #pragma unroll
        for (int i = 0; i < 4; i++)
            #pragma unroll
            for (int r = 0; r < 4; r++) {
                float s = 0.f;
                #pragma unroll
                for (int j = 0; j < 4; j++) s = fmaf(acc[i][j][r], acc[i][j][r], s);
                #pragma unroll
                for (int mm = 8; mm; mm >>= 1) s += __shfl_xor(s, mm);
                ssp[i][r] = s;
            }
        float* ss_s = (float*)a_s;
        if (l15 == 0) {
            #pragma unroll
            for (int i = 0; i < 4; i++)
                *(float4*)&ss_s[wn * 128 + wm * 64 + i * 16 + quad * 4] =
                    make_float4(ssp[i][0], ssp[i][1], ssp[i][2], ssp[i][3]);
        }
        __syncthreads();
        float rfac[4][4];
        #pragma unroll
        for (int i = 0; i < 4; i++) {
            float4 s0 = *(const float4*)&ss_s[wm * 64 + i * 16 + quad * 4];
            float4 s1 = *(const float4*)&ss_s[128 + wm * 64 + i * 16 + quad * 4];
            rfac[i][0] = rsqrtf((s0.x + s1.x) * (1.f / HD) + 1e-6f);
            rfac[i][1] = rsqrtf((s0.y + s1.y) * (1.f / HD) + 1e-6f);
            rfac[i][2] = rsqrtf((s0.z + s1.z) * (1.f / HD) + 1e-6f);
            rfac[i][3] = rsqrtf((s0.w + s1.w) * (1.f / HD) + 1e-6f);
        }
        const float* scale = mq ? k_scale : q_scale;
        float sgn = (l15 & 1) ? 1.f : -1.f;
        u16* obase = qkbf + (size_t)(mq * NH + h) * L_SEQ * HD;
        #pragma unroll
        for (int j = 0; j < 4; j++) {
            int d = wn * 64 + j * 16 + l15;
            float sd = scale[d];
            #pragma unroll
            for (int i = 0; i < 4; i++)
                #pragma unroll
                for (int r = 0; r < 4; r++) {
                    int row = bm + wm * 64 + i * 16 + quad * 4 + r;
                    float t = acc[i][j][r] * rfac[i][r] * sd;
                    float tp = __shfl_xor(t, 1);
                    float2 cs = pe2[row * 64 + (d >> 1)];
                    float o = fmaf(cs.x, t, sgn * cs.y * tp);
                    obase[(size_t)row * HD + d] = f2bf(o);
                }
        }
    }
}

// ---------------------------------------------------------------------------
// bf16 MFMA flash attention, FIXED-max softmax (M = 64 log2-units; safe since
// RMSNorm bounds |q|=|k|=sqrt(128) -> |s|*sc <= 16.4 log2; fp is scale-free so
// the offset costs no precision). No online rescale, no per-iter shfls.
// K/V LDS is double-buffered with the same 2-deep counted-vmcnt pipeline as
// the GEMM: issue tile t+1's 8 global_load_lds, vmcnt(8) retires tile t's
// (issued a full iteration earlier), barrier, compute, barrier. This replaces
// the old {syncthreads; stage; syncthreads-drain} which exposed the full
// staging latency every iteration. LDS 73 KB -> 2 blocks/CU.
// XCD-grouped dispatch: bid&7 = XCD owns 3 heads (KV L2-resident).
// ---------------------------------------------------------------------------
__global__ __launch_bounds__(256) void attn_mfma_kernel(
    const u16* __restrict__ qk_bf, const u16* __restrict__ vT, u16* __restrict__ Og)
{
    __shared__ __align__(16) u16 k_s[2][64 * 128];  // 32 KB, [kv][d] 16-chunk swizzled
    __shared__ __align__(16) u16 v_s[2][128 * 64];  // 32 KB, [d][kv] 8-chunk swizzled
    __shared__ __align__(16) u16 p_s[4][16 * 72];   // 9 KB per-wave P

    int bid = blockIdx.x;
    int loc = bid >> 3;
    int h = (bid & 7) * 3 + (loc >> 5);
    int q0 = (loc & 31) * 64;
    int tid = threadIdx.x;
    int wave = tid >> 6, lane = tid & 63;
    int quad = lane >> 4, l15 = lane & 15;
    const u16* qb = qk_bf + (size_t)h * L_SEQ * HD;
    const u16* kb = qk_bf + (size_t)(NH + h) * L_SEQ * HD;
    const u16* vTh = vT + (size_t)h * HD * L_SEQ;

    bf16x8 aq[4];
    {
        const u16* qr = qb + (size_t)(q0 + wave * 16 + l15) * HD + quad * 8;
        #pragma unroll
        for (int ks = 0; ks < 4; ks++) aq[ks] = *(const bf16x8*)(qr + ks * 32);
    }

    f32x4 o_acc[8];
    #pragma unroll
    for (int n = 0; n < 8; n++) o_acc[n] = (f32x4){0.f, 0.f, 0.f, 0.f};
    float lsum[4] = {0.f, 0.f, 0.f, 0.f};
    const float sc = 0.08838834764831845f * 1.4426950408889634f;  // /sqrt(128)*log2e
    const float MB = 64.0f;                                       // fixed max, log2 units

    const u16* gk[4];
    u16* lK[4];
    #pragma unroll
    for (int e = 0; e < 4; e++) {
        int r = wave * 16 + e * 4 + (lane >> 4);
        int g = l15 ^ (r & 15);
        gk[e] = kb + (size_t)r * HD + g * 8;
        lK[e] = &k_s[0][(wave * 16 + e * 4) * 128];
    }
    const u16* gv[4];
    u16* lV[4];
    #pragma unroll
    for (int e = 0; e < 4; e++) {
        int d = wave * 32 + e * 8 + (lane >> 3);
        gv[e] = vTh + (size_t)d * L_SEQ + (lane & 7) * 8;
        lV[e] = &v_s[0][(wave * 32 + e * 8) * 64];
    }
    int vco[2];
    #pragma unroll
    for (int ks = 0; ks < 2; ks++) vco[ks] = ((ks * 4 + quad) ^ (l15 & 7)) * 8;

    // prologue: issue tile 0 (no wait; iter 0's vmcnt(8) retires these)
    #pragma unroll
    for (int e = 0; e < 4; e++) {
        GLOBAL_TO_LDS16(gk[e], lK[e]);
        GLOBAL_TO_LDS16(gv[e], lV[e]);
    }

    const int NT = L_SEQ / 64;   // 32
    for (int t = 0; t < NT; ++t) {
        int cur = t & 1;
        int kcb = cur * (64 * 128);
        int vcb = cur * (128 * 64);
        if (t + 1 < NT) {
            int kv1 = (t + 1) * 64;
            int nk = (cur ^ 1) * (64 * 128);
            int nv = (cur ^ 1) * (128 * 64);
            #pragma unroll
            for (int e = 0; e < 4; e++) {
                GLOBAL_TO_LDS16(gk[e] + (size_t)kv1 * HD, lK[e] + nk);
                GLOBAL_TO_LDS16(gv[e] + kv1, lV[e] + nv);
            }
            asm volatile("s_waitcnt vmcnt(8)" ::: "memory");
        } else {
            asm volatile("s_waitcnt vmcnt(0)" ::: "memory");
        }
        __builtin_amdgcn_s_barrier();   // tile t fully staged for all waves

        // S = Q K^T
        f32x4 sacc[4];
        #pragma unroll
        for (int j = 0; j < 4; j++) sacc[j] = (f32x4){0.f, 0.f, 0.f, 0.f};
        __builtin_amdgcn_s_setprio(1);
        #pragma unroll
        for (int ks = 0; ks < 4; ks++) {
            #pragma unroll
            for (int j = 0; j < 4; j++) {
                int n = j * 16 + l15;
                int slot = (ks * 4 + quad) ^ (n & 15);
                bf16x8 bk = *(const bf16x8*)&k_s[0][kcb + n * 128 + slot * 8];
                sacc[j] = __builtin_amdgcn_mfma_f32_16x16x32_bf16(aq[ks], bk, sacc[j], 0, 0, 0);
            }
        }
        __builtin_amdgcn_s_setprio(0);

        // p = exp2(s*sc - MB); accumulate row sums; write P to LDS
        #pragma unroll
        for (int j = 0; j < 4; j++)
            #pragma unroll
            for (int r = 0; r < 4; r++) {
                float p = exp2f(fmaf(sacc[j][r], sc, -MB));
                sacc[j][r] = p;
                lsum[r] += p;
                p_s[wave][(quad * 4 + r) * 72 + j * 16 + l15] = f2bf(p);
            }
        bf16x8 ap[2];
        #pragma unroll
        for (int ks = 0; ks < 2; ks++)
            ap[ks] = *(const bf16x8*)&p_s[wave][l15 * 72 + ks * 32 + quad * 8];

        // O += P V  (no rescale — fixed max)
        __builtin_amdgcn_s_setprio(1);
        #pragma unroll
        for (int ks = 0; ks < 2; ks++) {
            #pragma unroll
            for (int n = 0; n < 8; n++) {
                bf16x8 bv = *(const bf16x8*)&v_s[0][vcb + (n * 16 + l15) * 64 + vco[ks]];
                o_acc[n] = __builtin_amdgcn_mfma_f32_16x16x32_bf16(ap[ks], bv, o_acc[n], 0, 0, 0);
            }
        }
        __builtin_amdgcn_s_setprio(0);
        // all waves done reading buf[cur] before t+1 stages tile t+2 into it
        __builtin_amdgcn_s_barrier();
    }

    // single end-of-loop row-sum reduction across the 16-lane groups
    #pragma unroll
    for (int r = 0; r < 4; r++) {
        #pragma unroll
        for (int mm = 8; mm; mm >>= 1) lsum[r] += __shfl_xor(lsum[r], mm);
    }

    #pragma unroll
    for (int r = 0; r < 4; r++) {
        float inv = 1.f / lsum[r];
        int row = q0 + wave * 16 + quad * 4 + r;
        u16* orow = Og + (size_t)row * KE + h * HD;
        #pragma unroll
        for (int n = 0; n < 8; n++)
            orow[n * 16 + l15] = f2bf(o_acc[n][r] * inv);
    }
}

// ---------------------------------------------------------------------------
extern "C" void kernel_launch(void* const* d_in, const int* in_sizes, int n_in,
                              void* d_out, int out_size, void* d_ws, size_t ws_size,
                              hipStream_t stream)
{
    const float* x         = (const float*)d_in[0];
    const float* pe        = (const float*)d_in[1];
    const float* qkv_w     = (const float*)d_in[2];
    const float* qkv_b     = (const float*)d_in[3];
    const float* proj_w    = (const float*)d_in[4];
    const float* proj_b    = (const float*)d_in[5];
    const float* qkv_down  = (const float*)d_in[6];
    const float* qkv_up    = (const float*)d_in[7];
    const float* proj_down = (const float*)d_in[8];
    const float* proj_up   = (const float*)d_in[9];
    const float* q_scale   = (const float*)d_in[10];
    const float* k_scale   = (const float*)d_in[11];
    float* out = (float*)d_out;

    char* w = (char*)d_ws;
    u16*   qk_bf  = (u16*)w;    w += (size_t)2 * NH * L_SEQ * HD * 2;  // 25.2 MB
    u16*   vT_bf  = (u16*)w;    w += (size_t)NH * HD * L_SEQ * 2;      // 12.6 MB
    u16*   x_ext  = (u16*)w;    w += (size_t)L_SEQ * KE * 2;           // 12.8 MB
    u16*   wq_ext = (u16*)w;    w += (size_t)N_QKV * KE * 2;           // 57.8 MB
    u16*   wp_ext = (u16*)w;    w += (size_t)DIM * KE * 2;             // 19.3 MB
    u16*   o_ext  = (u16*)w;    w += (size_t)L_SEQ * KE * 2;           // 12.8 MB
    float2* pe2   = (float2*)w; w += (size_t)L_SEQ * 64 * sizeof(float2);
    float* t1     = (float*)w;  w += (size_t)L_SEQ * RANK * 4;
    float* t2     = (float*)w;

    pack_pe_kernel<<<L_SEQ, 64, 0, stream>>>(pe, pe2);
    pack_w_kernel<<<N_QKV, 256, 0, stream>>>(qkv_w, qkv_up, wq_ext);
    pack_w_kernel<<<DIM, 256, 0, stream>>>(proj_w, proj_up, wp_ext);
    lora_down_kernel<<<L_SEQ, 256, 0, stream>>>(x, qkv_down, t1);
    pack_x_kernel<<<L_SEQ, 256, 0, stream>>>(x, t1, x_ext);

    gemm_mfma_kernel<1><<<(N_QKV / 128) * (L_SEQ / 128), 256, 0, stream>>>(
        x_ext, wq_ext, qkv_b, nullptr, qk_bf, vT_bf, pe2, q_scale, k_scale,
        L_SEQ, N_QKV, KE);
    attn_mfma_kernel<<<(L_SEQ / 64) * NH, 256, 0, stream>>>(qk_bf, vT_bf, o_ext);
    lora_down_bf_kernel<<<L_SEQ, 256, 0, stream>>>(o_ext, proj_down, t2, KE);
    pack_t_kernel<<<L_SEQ, 64, 0, stream>>>(t2, o_ext);
    gemm_mfma_kernel<0><<<(DIM / 128) * (L_SEQ / 128), 256, 0, stream>>>(
        o_ext, wp_ext, proj_b, out, nullptr, nullptr, nullptr, nullptr, nullptr,
        L_SEQ, DIM, KE);
}

// Round 6
// 671.337 us; speedup vs baseline: 1.2421x; 1.0630x over previous
//
#include <hip/hip_runtime.h>
#include <math.h>

#define L_SEQ 2048
#define DIM   3072
#define NH    24
#define HD    128
#define RANK  16
#define N_QKV 9216
#define KE    3136   // DIM + 16 (T_hi|Up) + 16 (T_lo|Up) + 32 zero pad; 64 | KE

typedef __attribute__((ext_vector_type(8))) short bf16x8;
typedef __attribute__((ext_vector_type(4))) float f32x4;
typedef unsigned short u16;
typedef unsigned int u32;

__device__ __forceinline__ u16 f2bf(float f) {
    union { float f; u32 u; } v; v.f = f;
    return (u16)((v.u + 0x7fffu + ((v.u >> 16) & 1u)) >> 16);
}
__device__ __forceinline__ float bf2f(u16 h) {
    union { u32 u; float f; } v; v.u = ((u32)h) << 16; return v.f;
}

#define GLOBAL_TO_LDS16(gp, lp) \
  __builtin_amdgcn_global_load_lds((const __attribute__((address_space(1))) u32*)(gp), \
                                   (__attribute__((address_space(3))) u32*)(lp), 16, 0, 0)

// ---------------------------------------------------------------------------
// pe [1,1,L,64,2,2] -> pe2 [L][64] (cos, sin)
// ---------------------------------------------------------------------------
__global__ __launch_bounds__(64) void pack_pe_kernel(
    const float* __restrict__ pe, float2* __restrict__ pe2)
{
    int l = blockIdx.x, i = threadIdx.x;
    int base = l * 256 + i * 4;
    float2 cs; cs.x = pe[base]; cs.y = pe[base + 2];
    pe2[l * 64 + i] = cs;
}

// ---------------------------------------------------------------------------
// T[l][r] = dot(X[l,:DIM], W[r,:DIM])  rank-16 LoRA down (fp32 X)
// ---------------------------------------------------------------------------
__global__ __launch_bounds__(256) void lora_down_kernel(
    const float* __restrict__ X, const float* __restrict__ W, float* __restrict__ T)
{
    int l = blockIdx.x;
    int r = threadIdx.x >> 4;
    int lane = threadIdx.x & 15;
    const float* xr = X + (size_t)l * DIM;
    const float* wr = W + (size_t)r * DIM;
    float s = 0.f;
    for (int k = lane; k < DIM; k += 16) s = fmaf(xr[k], wr[k], s);
    #pragma unroll
    for (int mm = 8; mm; mm >>= 1) s += __shfl_xor(s, mm);
    if (lane == 0) T[l * RANK + r] = s;
}

// bf16-X variant with row pitch (for o_ext)
__global__ __launch_bounds__(256) void lora_down_bf_kernel(
    const u16* __restrict__ X, const float* __restrict__ W, float* __restrict__ T, int pitch)
{
    int l = blockIdx.x;
    int r = threadIdx.x >> 4;
    int lane = threadIdx.x & 15;
    const u16* xr = X + (size_t)l * pitch;
    const float* wr = W + (size_t)r * DIM;
    float s = 0.f;
    for (int k = lane; k < DIM; k += 16) s = fmaf(bf2f(xr[k]), wr[k], s);
    #pragma unroll
    for (int mm = 8; mm; mm >>= 1) s += __shfl_xor(s, mm);
    if (lane == 0) T[l * RANK + r] = s;
}

// ---------------------------------------------------------------------------
// pack weights: [0:DIM)=bf16(W), [DIM,DIM+16)=Up, [DIM+16,DIM+32)=Up, pad=0
// ---------------------------------------------------------------------------
__global__ __launch_bounds__(256) void pack_w_kernel(
    const float* __restrict__ W, const float* __restrict__ Up, u16* __restrict__ out)
{
    int row = blockIdx.x;
    const float* wr = W + (size_t)row * DIM;
    u16* orow = out + (size_t)row * KE;
    #pragma unroll
    for (int it = 0; it < 3; it++) {
        int c4 = threadIdx.x + it * 256;
        float4 v = ((const float4*)wr)[c4];
        ushort4 o = {f2bf(v.x), f2bf(v.y), f2bf(v.z), f2bf(v.w)};
        *(ushort4*)(orow + c4 * 4) = o;
    }
    int t = threadIdx.x;
    if (t < RANK) {
        u16 b = f2bf(Up[row * RANK + t]);
        orow[DIM + t] = b;
        orow[DIM + RANK + t] = b;
    } else if (t >= 32 && t < 64) {
        orow[DIM + t] = 0;
    }
}

// pack activations: [0:DIM)=bf16(X), then T hi/lo, pad=0
__global__ __launch_bounds__(256) void pack_x_kernel(
    const float* __restrict__ X, const float* __restrict__ T, u16* __restrict__ out)
{
    int row = blockIdx.x;
    const float* xr = X + (size_t)row * DIM;
    u16* orow = out + (size_t)row * KE;
    #pragma unroll
    for (int it = 0; it < 3; it++) {
        int c4 = threadIdx.x + it * 256;
        float4 v = ((const float4*)xr)[c4];
        ushort4 o = {f2bf(v.x), f2bf(v.y), f2bf(v.z), f2bf(v.w)};
        *(ushort4*)(orow + c4 * 4) = o;
    }
    int t = threadIdx.x;
    if (t < RANK) {
        float tv = T[row * RANK + t];
        u16 hi = f2bf(tv);
        orow[DIM + t] = hi;
        orow[DIM + RANK + t] = f2bf(tv - bf2f(hi));
    } else if (t >= 32 && t < 64) {
        orow[DIM + t] = 0;
    }
}

// write T hi/lo + zero pad into existing bf16 [row][KE] buffer (o_ext)
__global__ __launch_bounds__(64) void pack_t_kernel(
    const float* __restrict__ T, u16* __restrict__ out)
{
    int row = blockIdx.x, t = threadIdx.x;
    u16* orow = out + (size_t)row * KE;
    if (t < RANK) {
        float tv = T[row * RANK + t];
        u16 hi = f2bf(tv);
        orow[DIM + t] = hi;
        orow[DIM + RANK + t] = f2bf(tv - bf2f(hi));
    } else if (t >= 32) {
        orow[DIM + t] = 0;
    }
}

// ---------------------------------------------------------------------------
// bf16 MFMA GEMM, 128x128 tile, BK=64, double-buffered LDS (64 KB), LoRA
// folded into K. 512 threads / 8 waves per block (wave grid 4M x 2N, each
// wave owns 32x64): 2 blocks/CU x 8 waves = 16 waves/CU = 4 waves/SIMD,
// double the wave-level concurrency of the 256-thread variant (R3/R5 were
// stuck at 2 waves/SIMD with both pipes <30% busy -> concurrency-bound).
// K-loop is the 2-deep counted-vmcnt pipeline (R5, neutral-vs-R3 but keeps
// loads in flight): issue tile t+1's 4 loads/thread, s_waitcnt vmcnt(4)
// retires tile t's, barrier, MFMA, barrier. vmcnt never drains mid-loop.
// Block mapping is XCD-aware (bid&7 = XCD heuristic): each XCD owns a
// 4-mtile x (num_n/2) rectangle; m-inner order keeps its 3.2 MB A slab
// L2-resident while each W n-slab is consumed by 4 co-resident blocks once.
// MODE 0: C = A@W^T + bias -> fp32 [M][N]  (proj)
// MODE 1: qkv with fused RMSNorm+RoPE epilogue (q,k bf16 [2][NH][L][HD];
//   v bf16 [NH][HD][L] swizzled).
// ---------------------------------------------------------------------------
template<int MODE>
__global__ __launch_bounds__(512) void gemm_mfma_kernel(
    const u16* __restrict__ A, const u16* __restrict__ W,
    const float* __restrict__ bias,
    float* __restrict__ Cf,
    u16* __restrict__ qkbf, u16* __restrict__ vT,
    const float2* __restrict__ pe2,
    const float* __restrict__ q_scale, const float* __restrict__ k_scale,
    int M, int N, int K)
{
    __shared__ __align__(16) u16 a_s[2][128 * 64];   // 32 KB (dbuf)
    __shared__ __align__(16) u16 b_s[2][128 * 64];   // 32 KB (dbuf)

    int tid = threadIdx.x;
    int wave = tid >> 6, lane = tid & 63;
    int quad = lane >> 4, l15 = lane & 15;
    int wm = wave >> 1, wn = wave & 1;               // 4M x 2N wave grid

    // XCD-aware mapping: num_m must be 16, num_n even.
    int num_n = N >> 7;
    int xcd = blockIdx.x & 7;
    int loc = blockIdx.x >> 3;
    int bm = (((xcd & 3) << 2) + (loc & 3)) << 7;
    int bn = ((xcd >> 2) * (num_n >> 1) + (loc >> 2)) << 7;

    // staging: 2 issues per matrix per thread; 64 rows x 128 B per issue;
    // chunk XOR swizzle (row&7) matches the read-side co[] swizzle.
    const u16* ga[2]; const u16* gb[2];
    u16 *lA[2], *lB[2];
    #pragma unroll
    for (int e = 0; e < 2; e++) {
        int r = e * 64 + (tid >> 3);
        int g = (tid & 7) ^ (r & 7);
        ga[e] = A + (size_t)(bm + r) * K + g * 8;
        gb[e] = W + (size_t)(bn + r) * K + g * 8;
        lA[e] = &a_s[0][(e * 64 + wave * 8) * 64];
        lB[e] = &b_s[0][(e * 64 + wave * 8) * 64];
    }

    f32x4 acc[2][4];
    #pragma unroll
    for (int i = 0; i < 2; i++)
        #pragma unroll
        for (int j = 0; j < 4; j++) acc[i][j] = (f32x4){0.f, 0.f, 0.f, 0.f};

    int abase[2], bbase[4], co[2];
    #pragma unroll
    for (int i = 0; i < 2; i++) abase[i] = (wm * 32 + i * 16 + l15) * 64;
    #pragma unroll
    for (int j = 0; j < 4; j++) bbase[j] = (wn * 64 + j * 16 + l15) * 64;
    #pragma unroll
    for (int ks = 0; ks < 2; ks++) co[ks] = ((ks * 4 + quad) ^ (l15 & 7)) * 8;

    // prologue: issue tile 0 into buffer 0 (no wait; iter 0's vmcnt(4)
    // retires these 4 after issuing tile 1)
    #pragma unroll
    for (int e = 0; e < 2; e++) {
        GLOBAL_TO_LDS16(ga[e], lA[e]);
        GLOBAL_TO_LDS16(gb[e], lB[e]);
    }

    int nt = K >> 6;
    for (int t = 0; t < nt; ++t) {
        int cur = t & 1;
        int cb = cur * 8192;
        int nb = (cur ^ 1) * 8192;
        if (t + 1 < nt) {
            // issue tile t+1, then wait only for tile t's 4 loads; the 4
            // newest (t+1) stay in flight across the barrier + compute
            int ko = (t + 1) << 6;
            #pragma unroll
            for (int e = 0; e < 2; e++) {
                GLOBAL_TO_LDS16(ga[e] + ko, lA[e] + nb);
                GLOBAL_TO_LDS16(gb[e] + ko, lB[e] + nb);
            }
            asm volatile("s_waitcnt vmcnt(4)" ::: "memory");
        } else {
            asm volatile("s_waitcnt vmcnt(0)" ::: "memory");
        }
        __builtin_amdgcn_s_barrier();   // all waves' tile-t stages landed
        __builtin_amdgcn_s_setprio(1);
        #pragma unroll
        for (int ks = 0; ks < 2; ks++) {
            bf16x8 af[2], bf[4];
            #pragma unroll
            for (int i = 0; i < 2; i++) af[i] = *(const bf16x8*)&a_s[0][cb + abase[i] + co[ks]];
            #pragma unroll
            for (int j = 0; j < 4; j++) bf[j] = *(const bf16x8*)&b_s[0][cb + bbase[j] + co[ks]];
            #pragma unroll
            for (int i = 0; i < 2; i++)
                #pragma unroll
                for (int j = 0; j < 4; j++)
                    acc[i][j] = __builtin_amdgcn_mfma_f32_16x16x32_bf16(af[i], bf[j], acc[i][j], 0, 0, 0);
        }
        __builtin_amdgcn_s_setprio(0);
        // all waves done reading buf[cur] before t+1 stages tile t+2 into it
        __builtin_amdgcn_s_barrier();
    }

    if (MODE == 0) {
        #pragma unroll
        for (int j = 0; j < 4; j++) {
            int col = bn + wn * 64 + j * 16 + l15;
            float bj = bias[col];
            #pragma unroll
            for (int i = 0; i < 2; i++)
                #pragma unroll
                for (int r = 0; r < 4; r++) {
                    int row = bm + wm * 32 + i * 16 + quad * 4 + r;
                    Cf[(size_t)row * N + col] = acc[i][j][r] + bj;
                }
        }
        return;
    }

    // ---- MODE 1: fused qkv epilogue ----
    int tn = bn >> 7;
    int mq = (tn >= 48) ? 2 : (tn >= 24 ? 1 : 0);
    int h = tn - mq * 24;

    #pragma unroll
    for (int j = 0; j < 4; j++) {
        float bj = bias[bn + wn * 64 + j * 16 + l15];
        #pragma unroll
        for (int i = 0; i < 2; i++)
            #pragma unroll
            for (int r = 0; r < 4; r++) acc[i][j][r] += bj;
    }

    if (mq == 2) {
        // V: store transposed [h][d][L] with chunk swizzle baked in
        #pragma unroll
        for (int j = 0; j < 4; j++) {
            int d = wn * 64 + j * 16 + l15;
            u16* vrow = vT + ((size_t)h * HD + d) * L_SEQ;
            #pragma unroll
            for (int i = 0; i < 2; i++)
                #pragma unroll
                for (int r = 0; r < 4; r++) {
                    int kv = bm + wm * 32 + i * 16 + quad * 4 + r;
                    int slot = ((kv >> 3) & 7) ^ (d & 7);
                    int colp = (kv & ~63) + slot * 8 + (kv & 7);
                    vrow[colp] = f2bf(acc[i][j][r]);
                }
        }
    } else {
        // per-row sum of squares over this wave's 64 cols; reduce across the
        // wn pair (cols 0-63 | 64-127) via 256-float LDS scratch.
        float ssp[2][4];
        #pragma unroll
        for (int i = 0; i < 2; i++)
            #pragma unroll
            for (int r = 0; r < 4; r++) {
                float s = 0.f;
                #pragma unroll
                for (int j = 0; j < 4; j++) s = fmaf(acc[i][j][r], acc[i][j][r], s);
                #pragma unroll
                for (int mm = 8; mm; mm >>= 1) s += __shfl_xor(s, mm);
                ssp[i][r] = s;
            }
        float* ss_s = (float*)a_s;   // 1 KB scratch; K-loop done (drained)
        if (l15 == 0) {
            #pragma unroll
            for (int i = 0; i < 2; i++)
                *(float4*)&ss_s[wn * 128 + wm * 32 + i * 16 + quad * 4] =
                    make_float4(ssp[i][0], ssp[i][1], ssp[i][2], ssp[i][3]);
        }
        __syncthreads();
        float rfac[2][4];
        #pragma unroll
        for (int i = 0; i < 2; i++) {
            int base = wm * 32 + i * 16 + quad * 4;
            float4 s0 = *(const float4*)&ss_s[base];
            float4 s1 = *(const float4*)&ss_s[128 + base];
            rfac[i][0] = rsqrtf((s0.x + s1.x) * (1.f / HD) + 1e-6f);
            rfac[i][1] = rsqrtf((s0.y + s1.y) * (1.f / HD) + 1e-6f);
            rfac[i][2] = rsqrtf((s0.z + s1.z) * (1.f / HD) + 1e-6f);
            rfac[i][3] = rsqrtf((s0.w + s1.w) * (1.f / HD) + 1e-6f);
        }
        const float* scale = mq ? k_scale : q_scale;
        float sgn = (l15 & 1) ? 1.f : -1.f;
        u16* obase = qkbf + (size_t)(mq * NH + h) * L_SEQ * HD;
        #pragma unroll
        for (int j = 0; j < 4; j++) {
            int d = wn * 64 + j * 16 + l15;
            float sd = scale[d];
            #pragma unroll
            for (int i = 0; i < 2; i++)
                #pragma unroll
                for (int r = 0; r < 4; r++) {
                    int row = bm + wm * 32 + i * 16 + quad * 4 + r;
                    float t = acc[i][j][r] * rfac[i][r] * sd;
                    float tp = __shfl_xor(t, 1);
                    float2 cs = pe2[row * 64 + (d >> 1)];
                    float o = fmaf(cs.x, t, sgn * cs.y * tp);
                    obase[(size_t)row * HD + d] = f2bf(o);
                }
        }
    }
}

// ---------------------------------------------------------------------------
// bf16 MFMA flash attention, FIXED-max softmax (M = 64 log2-units; safe since
// RMSNorm bounds |q|=|k|=sqrt(128) -> |s|*sc <= 16.4 log2; fp is scale-free so
// the offset costs no precision). No online rescale, no per-iter shfls.
// Single-buffered (R3 form): 41 KB LDS -> 3 blocks/CU = 12 waves/CU; the
// dbuf variant (R5) cost a block of occupancy and regressed ~24 us.
// XCD-grouped dispatch: bid&7 = XCD owns 3 heads (KV L2-resident).
// ---------------------------------------------------------------------------
__global__ __launch_bounds__(256) void attn_mfma_kernel(
    const u16* __restrict__ qk_bf, const u16* __restrict__ vT, u16* __restrict__ Og)
{
    __shared__ __align__(16) u16 k_s[64 * 128];    // 16 KB, [kv][d] 16-chunk swizzled
    __shared__ __align__(16) u16 v_s[128 * 64];    // 16 KB, [d][kv] 8-chunk swizzled
    __shared__ __align__(16) u16 p_s[4][16 * 72];  // 9 KB per-wave P

    int bid = blockIdx.x;
    int loc = bid >> 3;
    int h = (bid & 7) * 3 + (loc >> 5);
    int q0 = (loc & 31) * 64;
    int tid = threadIdx.x;
    int wave = tid >> 6, lane = tid & 63;
    int quad = lane >> 4, l15 = lane & 15;
    const u16* qb = qk_bf + (size_t)h * L_SEQ * HD;
    const u16* kb = qk_bf + (size_t)(NH + h) * L_SEQ * HD;
    const u16* vTh = vT + (size_t)h * HD * L_SEQ;

    bf16x8 aq[4];
    {
        const u16* qr = qb + (size_t)(q0 + wave * 16 + l15) * HD + quad * 8;
        #pragma unroll
        for (int ks = 0; ks < 4; ks++) aq[ks] = *(const bf16x8*)(qr + ks * 32);
    }

    f32x4 o_acc[8];
    #pragma unroll
    for (int n = 0; n < 8; n++) o_acc[n] = (f32x4){0.f, 0.f, 0.f, 0.f};
    float lsum[4] = {0.f, 0.f, 0.f, 0.f};
    const float sc = 0.08838834764831845f * 1.4426950408889634f;  // /sqrt(128)*log2e
    const float MB = 64.0f;                                       // fixed max, log2 units

    const u16* gk[4];
    #pragma unroll
    for (int e = 0; e < 4; e++) {
        int r = wave * 16 + e * 4 + (lane >> 4);
        int g = l15 ^ (r & 15);
        gk[e] = kb + (size_t)r * HD + g * 8;
    }
    const u16* gv[4];
    #pragma unroll
    for (int e = 0; e < 4; e++) {
        int d = wave * 32 + e * 8 + (lane >> 3);
        gv[e] = vTh + (size_t)d * L_SEQ + (lane & 7) * 8;
    }
    int vco[2];
    #pragma unroll
    for (int ks = 0; ks < 2; ks++) vco[ks] = ((ks * 4 + quad) ^ (l15 & 7)) * 8;

    for (int kv0 = 0; kv0 < L_SEQ; kv0 += 64) {
        __syncthreads();
        #pragma unroll
        for (int e = 0; e < 4; e++) {
            GLOBAL_TO_LDS16(gk[e] + (size_t)kv0 * HD, &k_s[(wave * 16 + e * 4) * 128]);
            GLOBAL_TO_LDS16(gv[e] + kv0, &v_s[(wave * 32 + e * 8) * 64]);
        }
        __syncthreads();

        // S = Q K^T
        f32x4 sacc[4];
        #pragma unroll
        for (int j = 0; j < 4; j++) sacc[j] = (f32x4){0.f, 0.f, 0.f, 0.f};
        #pragma unroll
        for (int ks = 0; ks < 4; ks++) {
            #pragma unroll
            for (int j = 0; j < 4; j++) {
                int n = j * 16 + l15;
                int slot = (ks * 4 + quad) ^ (n & 15);
                bf16x8 bk = *(const bf16x8*)&k_s[n * 128 + slot * 8];
                sacc[j] = __builtin_amdgcn_mfma_f32_16x16x32_bf16(aq[ks], bk, sacc[j], 0, 0, 0);
            }
        }

        // p = exp2(s*sc - MB); accumulate row sums; write P to LDS
        #pragma unroll
        for (int j = 0; j < 4; j++)
            #pragma unroll
            for (int r = 0; r < 4; r++) {
                float p = exp2f(fmaf(sacc[j][r], sc, -MB));
                sacc[j][r] = p;
                lsum[r] += p;
                p_s[wave][(quad * 4 + r) * 72 + j * 16 + l15] = f2bf(p);
            }
        bf16x8 ap[2];
        #pragma unroll
        for (int ks = 0; ks < 2; ks++)
            ap[ks] = *(const bf16x8*)&p_s[wave][l15 * 72 + ks * 32 + quad * 8];

        // O += P V  (no rescale — fixed max)
        #pragma unroll
        for (int ks = 0; ks < 2; ks++) {
            #pragma unroll
            for (int n = 0; n < 8; n++) {
                bf16x8 bv = *(const bf16x8*)&v_s[(n * 16 + l15) * 64 + vco[ks]];
                o_acc[n] = __builtin_amdgcn_mfma_f32_16x16x32_bf16(ap[ks], bv, o_acc[n], 0, 0, 0);
            }
        }
    }

    // single end-of-loop row-sum reduction across the 16-lane groups
    #pragma unroll
    for (int r = 0; r < 4; r++) {
        #pragma unroll
        for (int mm = 8; mm; mm >>= 1) lsum[r] += __shfl_xor(lsum[r], mm);
    }

    #pragma unroll
    for (int r = 0; r < 4; r++) {
        float inv = 1.f / lsum[r];
        int row = q0 + wave * 16 + quad * 4 + r;
        u16* orow = Og + (size_t)row * KE + h * HD;
        #pragma unroll
        for (int n = 0; n < 8; n++)
            orow[n * 16 + l15] = f2bf(o_acc[n][r] * inv);
    }
}

// ---------------------------------------------------------------------------
extern "C" void kernel_launch(void* const* d_in, const int* in_sizes, int n_in,
                              void* d_out, int out_size, void* d_ws, size_t ws_size,
                              hipStream_t stream)
{
    const float* x         = (const float*)d_in[0];
    const float* pe        = (const float*)d_in[1];
    const float* qkv_w     = (const float*)d_in[2];
    const float* qkv_b     = (const float*)d_in[3];
    const float* proj_w    = (const float*)d_in[4];
    const float* proj_b    = (const float*)d_in[5];
    const float* qkv_down  = (const float*)d_in[6];
    const float* qkv_up    = (const float*)d_in[7];
    const float* proj_down = (const float*)d_in[8];
    const float* proj_up   = (const float*)d_in[9];
    const float* q_scale   = (const float*)d_in[10];
    const float* k_scale   = (const float*)d_in[11];
    float* out = (float*)d_out;

    char* w = (char*)d_ws;
    u16*   qk_bf  = (u16*)w;    w += (size_t)2 * NH * L_SEQ * HD * 2;  // 25.2 MB
    u16*   vT_bf  = (u16*)w;    w += (size_t)NH * HD * L_SEQ * 2;      // 12.6 MB
    u16*   x_ext  = (u16*)w;    w += (size_t)L_SEQ * KE * 2;           // 12.8 MB
    u16*   wq_ext = (u16*)w;    w += (size_t)N_QKV * KE * 2;           // 57.8 MB
    u16*   wp_ext = (u16*)w;    w += (size_t)DIM * KE * 2;             // 19.3 MB
    u16*   o_ext  = (u16*)w;    w += (size_t)L_SEQ * KE * 2;           // 12.8 MB
    float2* pe2   = (float2*)w; w += (size_t)L_SEQ * 64 * sizeof(float2);
    float* t1     = (float*)w;  w += (size_t)L_SEQ * RANK * 4;
    float* t2     = (float*)w;

    pack_pe_kernel<<<L_SEQ, 64, 0, stream>>>(pe, pe2);
    pack_w_kernel<<<N_QKV, 256, 0, stream>>>(qkv_w, qkv_up, wq_ext);
    pack_w_kernel<<<DIM, 256, 0, stream>>>(proj_w, proj_up, wp_ext);
    lora_down_kernel<<<L_SEQ, 256, 0, stream>>>(x, qkv_down, t1);
    pack_x_kernel<<<L_SEQ, 256, 0, stream>>>(x, t1, x_ext);

    gemm_mfma_kernel<1><<<(N_QKV / 128) * (L_SEQ / 128), 512, 0, stream>>>(
        x_ext, wq_ext, qkv_b, nullptr, qk_bf, vT_bf, pe2, q_scale, k_scale,
        L_SEQ, N_QKV, KE);
    attn_mfma_kernel<<<(L_SEQ / 64) * NH, 256, 0, stream>>>(qk_bf, vT_bf, o_ext);
    lora_down_bf_kernel<<<L_SEQ, 256, 0, stream>>>(o_ext, proj_down, t2, KE);
    pack_t_kernel<<<L_SEQ, 64, 0, stream>>>(t2, o_ext);
    gemm_mfma_kernel<0><<<(DIM / 128) * (L_SEQ / 128), 512, 0, stream>>>(
        o_ext, wp_ext, proj_b, out, nullptr, nullptr, nullptr, nullptr, nullptr,
        L_SEQ, DIM, KE);
}

// Round 7
// 668.436 us; speedup vs baseline: 1.2475x; 1.0043x over previous
//
#include <hip/hip_runtime.h>
#include <math.h>

#define L_SEQ 2048
#define DIM   3072
#define NH    24
#define HD    128
#define RANK  16
#define N_QKV 9216
#define KE    3136   // DIM + 16 (T_hi|Up) + 16 (T_lo|Up) + 32 zero pad; 64 | KE

typedef __attribute__((ext_vector_type(8))) short bf16x8;
typedef __attribute__((ext_vector_type(4))) float f32x4;
typedef unsigned short u16;
typedef unsigned int u32;

__device__ __forceinline__ u16 f2bf(float f) {
    union { float f; u32 u; } v; v.f = f;
    return (u16)((v.u + 0x7fffu + ((v.u >> 16) & 1u)) >> 16);
}
__device__ __forceinline__ float bf2f(u16 h) {
    union { u32 u; float f; } v; v.u = ((u32)h) << 16; return v.f;
}

#define GLOBAL_TO_LDS16(gp, lp) \
  __builtin_amdgcn_global_load_lds((const __attribute__((address_space(1))) u32*)(gp), \
                                   (__attribute__((address_space(3))) u32*)(lp), 16, 0, 0)

// ---------------------------------------------------------------------------
// Fused prep: pack both weight matrices + pe, one launch.
// grid = [0,N_QKV) qkv rows | [N_QKV,N_QKV+DIM) proj rows | 512 pe blocks
// ---------------------------------------------------------------------------
__device__ __forceinline__ void pack_w_row(
    const float* __restrict__ W, const float* __restrict__ Up,
    u16* __restrict__ out, int row, int t)
{
    const float* wr = W + (size_t)row * DIM;
    u16* orow = out + (size_t)row * KE;
    #pragma unroll
    for (int it = 0; it < 3; it++) {
        int c4 = t + it * 256;
        float4 v = ((const float4*)wr)[c4];
        ushort4 o = {f2bf(v.x), f2bf(v.y), f2bf(v.z), f2bf(v.w)};
        *(ushort4*)(orow + c4 * 4) = o;
    }
    if (t < RANK) {
        u16 b = f2bf(Up[row * RANK + t]);
        orow[DIM + t] = b;
        orow[DIM + RANK + t] = b;
    } else if (t >= 32 && t < 64) {
        orow[DIM + t] = 0;
    }
}

__global__ __launch_bounds__(256) void prep_kernel(
    const float* __restrict__ qkv_w, const float* __restrict__ qkv_up,
    const float* __restrict__ proj_w, const float* __restrict__ proj_up,
    const float* __restrict__ pe,
    u16* __restrict__ wq_ext, u16* __restrict__ wp_ext,
    float2* __restrict__ pe2)
{
    int bid = blockIdx.x, t = threadIdx.x;
    if (bid < N_QKV) {
        pack_w_row(qkv_w, qkv_up, wq_ext, bid, t);
    } else if (bid < N_QKV + DIM) {
        pack_w_row(proj_w, proj_up, wp_ext, bid - N_QKV, t);
    } else {
        // pe: 512 blocks x 4 rows each; pe[1,1,L,64,2,2] -> pe2[L][64]
        int b = bid - (N_QKV + DIM);
        int l = b * 4 + (t >> 6);
        int i = t & 63;
        int base = l * 256 + i * 4;
        float2 cs; cs.x = pe[base]; cs.y = pe[base + 2];
        pe2[l * 64 + i] = cs;
    }
}

// ---------------------------------------------------------------------------
// Fused LoRA-down + pack_x: per row, compute T[16]=X_row . Down^T into LDS,
// then convert row to bf16 and append T hi/lo + zero pad. One launch, one
// pass over x (second read L1/L2-hot), no global T roundtrip.
// ---------------------------------------------------------------------------
__global__ __launch_bounds__(256) void lora_pack_x_kernel(
    const float* __restrict__ X, const float* __restrict__ Down,
    u16* __restrict__ out)
{
    __shared__ float T_s[RANK];
    int l = blockIdx.x, tid = threadIdx.x;
    int r = tid >> 4, lane = tid & 15;
    const float* xr = X + (size_t)l * DIM;
    const float* wr = Down + (size_t)r * DIM;
    float s = 0.f;
    for (int k = lane; k < DIM; k += 16) s = fmaf(xr[k], wr[k], s);
    #pragma unroll
    for (int mm = 8; mm; mm >>= 1) s += __shfl_xor(s, mm);
    if (lane == 0) T_s[r] = s;
    __syncthreads();

    u16* orow = out + (size_t)l * KE;
    #pragma unroll
    for (int it = 0; it < 3; it++) {
        int c4 = tid + it * 256;
        float4 v = ((const float4*)xr)[c4];
        ushort4 o = {f2bf(v.x), f2bf(v.y), f2bf(v.z), f2bf(v.w)};
        *(ushort4*)(orow + c4 * 4) = o;
    }
    if (tid < RANK) {
        float tv = T_s[tid];
        u16 hi = f2bf(tv);
        orow[DIM + tid] = hi;
        orow[DIM + RANK + tid] = f2bf(tv - bf2f(hi));
    } else if (tid >= 32 && tid < 64) {
        orow[DIM + tid] = 0;
    }
}

// ---------------------------------------------------------------------------
// Fused LoRA-down (bf16 O rows) + pack_t: compute T from o_ext row (already
// bf16, pitch KE), write T hi/lo + zero pad in place.
// ---------------------------------------------------------------------------
__global__ __launch_bounds__(256) void lora_pack_t_kernel(
    u16* __restrict__ O, const float* __restrict__ Down)
{
    __shared__ float T_s[RANK];
    int l = blockIdx.x, tid = threadIdx.x;
    int r = tid >> 4, lane = tid & 15;
    const u16* xr = O + (size_t)l * KE;
    const float* wr = Down + (size_t)r * DIM;
    float s = 0.f;
    for (int k = lane; k < DIM; k += 16) s = fmaf(bf2f(xr[k]), wr[k], s);
    #pragma unroll
    for (int mm = 8; mm; mm >>= 1) s += __shfl_xor(s, mm);
    if (lane == 0) T_s[r] = s;
    __syncthreads();

    u16* orow = O + (size_t)l * KE;
    if (tid < RANK) {
        float tv = T_s[tid];
        u16 hi = f2bf(tv);
        orow[DIM + tid] = hi;
        orow[DIM + RANK + tid] = f2bf(tv - bf2f(hi));
    } else if (tid >= 32 && tid < 64) {
        orow[DIM + tid] = 0;
    }
}

// ---------------------------------------------------------------------------
// bf16 MFMA GEMM, 128x128 tile, BK=64, double-buffered LDS (64 KB), LoRA
// folded into K. 512 threads / 8 waves per block (wave grid 4M x 2N, each
// wave owns 32x64): 2 blocks/CU x 8 waves = 16 waves/CU = 4 waves/SIMD.
// K-loop is the 2-deep counted-vmcnt pipeline: issue tile t+1's 4 loads per
// thread, s_waitcnt vmcnt(4) retires tile t's, barrier, MFMA, barrier.
// vmcnt never drains mid-loop. At ~696 TF this sits at the documented
// 2-phase-structure ceiling; 8-phase/256-tile cannot pack this grid (R4).
// Block mapping is XCD-aware (bid&7 = XCD heuristic).
// MODE 0: C = A@W^T + bias -> fp32 [M][N]  (proj)
// MODE 1: qkv with fused RMSNorm+RoPE epilogue (q,k bf16 [2][NH][L][HD];
//   v bf16 [NH][HD][L] swizzled).
// ---------------------------------------------------------------------------
template<int MODE>
__global__ __launch_bounds__(512) void gemm_mfma_kernel(
    const u16* __restrict__ A, const u16* __restrict__ W,
    const float* __restrict__ bias,
    float* __restrict__ Cf,
    u16* __restrict__ qkbf, u16* __restrict__ vT,
    const float2* __restrict__ pe2,
    const float* __restrict__ q_scale, const float* __restrict__ k_scale,
    int M, int N, int K)
{
    __shared__ __align__(16) u16 a_s[2][128 * 64];   // 32 KB (dbuf)
    __shared__ __align__(16) u16 b_s[2][128 * 64];   // 32 KB (dbuf)

    int tid = threadIdx.x;
    int wave = tid >> 6, lane = tid & 63;
    int quad = lane >> 4, l15 = lane & 15;
    int wm = wave >> 1, wn = wave & 1;               // 4M x 2N wave grid

    // XCD-aware mapping: num_m must be 16, num_n even.
    int num_n = N >> 7;
    int xcd = blockIdx.x & 7;
    int loc = blockIdx.x >> 3;
    int bm = (((xcd & 3) << 2) + (loc & 3)) << 7;
    int bn = ((xcd >> 2) * (num_n >> 1) + (loc >> 2)) << 7;

    // staging: 2 issues per matrix per thread; 64 rows x 128 B per issue;
    // chunk XOR swizzle (row&7) matches the read-side co[] swizzle.
    const u16* ga[2]; const u16* gb[2];
    u16 *lA[2], *lB[2];
    #pragma unroll
    for (int e = 0; e < 2; e++) {
        int r = e * 64 + (tid >> 3);
        int g = (tid & 7) ^ (r & 7);
        ga[e] = A + (size_t)(bm + r) * K + g * 8;
        gb[e] = W + (size_t)(bn + r) * K + g * 8;
        lA[e] = &a_s[0][(e * 64 + wave * 8) * 64];
        lB[e] = &b_s[0][(e * 64 + wave * 8) * 64];
    }

    f32x4 acc[2][4];
    #pragma unroll
    for (int i = 0; i < 2; i++)
        #pragma unroll
        for (int j = 0; j < 4; j++) acc[i][j] = (f32x4){0.f, 0.f, 0.f, 0.f};

    int abase[2], bbase[4], co[2];
    #pragma unroll
    for (int i = 0; i < 2; i++) abase[i] = (wm * 32 + i * 16 + l15) * 64;
    #pragma unroll
    for (int j = 0; j < 4; j++) bbase[j] = (wn * 64 + j * 16 + l15) * 64;
    #pragma unroll
    for (int ks = 0; ks < 2; ks++) co[ks] = ((ks * 4 + quad) ^ (l15 & 7)) * 8;

    // prologue: issue tile 0 into buffer 0 (no wait; iter 0's vmcnt(4)
    // retires these 4 after issuing tile 1)
    #pragma unroll
    for (int e = 0; e < 2; e++) {
        GLOBAL_TO_LDS16(ga[e], lA[e]);
        GLOBAL_TO_LDS16(gb[e], lB[e]);
    }

    int nt = K >> 6;
    for (int t = 0; t < nt; ++t) {
        int cur = t & 1;
        int cb = cur * 8192;
        int nb = (cur ^ 1) * 8192;
        if (t + 1 < nt) {
            // issue tile t+1, then wait only for tile t's 4 loads; the 4
            // newest (t+1) stay in flight across the barrier + compute
            int ko = (t + 1) << 6;
            #pragma unroll
            for (int e = 0; e < 2; e++) {
                GLOBAL_TO_LDS16(ga[e] + ko, lA[e] + nb);
                GLOBAL_TO_LDS16(gb[e] + ko, lB[e] + nb);
            }
            asm volatile("s_waitcnt vmcnt(4)" ::: "memory");
        } else {
            asm volatile("s_waitcnt vmcnt(0)" ::: "memory");
        }
        __builtin_amdgcn_s_barrier();   // all waves' tile-t stages landed
        __builtin_amdgcn_s_setprio(1);
        #pragma unroll
        for (int ks = 0; ks < 2; ks++) {
            bf16x8 af[2], bf[4];
            #pragma unroll
            for (int i = 0; i < 2; i++) af[i] = *(const bf16x8*)&a_s[0][cb + abase[i] + co[ks]];
            #pragma unroll
            for (int j = 0; j < 4; j++) bf[j] = *(const bf16x8*)&b_s[0][cb + bbase[j] + co[ks]];
            #pragma unroll
            for (int i = 0; i < 2; i++)
                #pragma unroll
                for (int j = 0; j < 4; j++)
                    acc[i][j] = __builtin_amdgcn_mfma_f32_16x16x32_bf16(af[i], bf[j], acc[i][j], 0, 0, 0);
        }
        __builtin_amdgcn_s_setprio(0);
        // all waves done reading buf[cur] before t+1 stages tile t+2 into it
        __builtin_amdgcn_s_barrier();
    }

    if (MODE == 0) {
        #pragma unroll
        for (int j = 0; j < 4; j++) {
            int col = bn + wn * 64 + j * 16 + l15;
            float bj = bias[col];
            #pragma unroll
            for (int i = 0; i < 2; i++)
                #pragma unroll
                for (int r = 0; r < 4; r++) {
                    int row = bm + wm * 32 + i * 16 + quad * 4 + r;
                    Cf[(size_t)row * N + col] = acc[i][j][r] + bj;
                }
        }
        return;
    }

    // ---- MODE 1: fused qkv epilogue ----
    int tn = bn >> 7;
    int mq = (tn >= 48) ? 2 : (tn >= 24 ? 1 : 0);
    int h = tn - mq * 24;

    #pragma unroll
    for (int j = 0; j < 4; j++) {
        float bj = bias[bn + wn * 64 + j * 16 + l15];
        #pragma unroll
        for (int i = 0; i < 2; i++)
            #pragma unroll
            for (int r = 0; r < 4; r++) acc[i][j][r] += bj;
    }

    if (mq == 2) {
        // V: store transposed [h][d][L] with chunk swizzle baked in
        #pragma unroll
        for (int j = 0; j < 4; j++) {
            int d = wn * 64 + j * 16 + l15;
            u16* vrow = vT + ((size_t)h * HD + d) * L_SEQ;
            #pragma unroll
            for (int i = 0; i < 2; i++)
                #pragma unroll
                for (int r = 0; r < 4; r++) {
                    int kv = bm + wm * 32 + i * 16 + quad * 4 + r;
                    int slot = ((kv >> 3) & 7) ^ (d & 7);
                    int colp = (kv & ~63) + slot * 8 + (kv & 7);
                    vrow[colp] = f2bf(acc[i][j][r]);
                }
        }
    } else {
        // per-row sum of squares over this wave's 64 cols; reduce across the
        // wn pair (cols 0-63 | 64-127) via 256-float LDS scratch.
        float ssp[2][4];
        #pragma unroll
        for (int i = 0; i < 2; i++)
            #pragma unroll
            for (int r = 0; r < 4; r++) {
                float s = 0.f;
                #pragma unroll
                for (int j = 0; j < 4; j++) s = fmaf(acc[i][j][r], acc[i][j][r], s);
                #pragma unroll
                for (int mm = 8; mm; mm >>= 1) s += __shfl_xor(s, mm);
                ssp[i][r] = s;
            }
        float* ss_s = (float*)a_s;   // 1 KB scratch; K-loop done (drained)
        if (l15 == 0) {
            #pragma unroll
            for (int i = 0; i < 2; i++)
                *(float4*)&ss_s[wn * 128 + wm * 32 + i * 16 + quad * 4] =
                    make_float4(ssp[i][0], ssp[i][1], ssp[i][2], ssp[i][3]);
        }
        __syncthreads();
        float rfac[2][4];
        #pragma unroll
        for (int i = 0; i < 2; i++) {
            int base = wm * 32 + i * 16 + quad * 4;
            float4 s0 = *(const float4*)&ss_s[base];
            float4 s1 = *(const float4*)&ss_s[128 + base];
            rfac[i][0] = rsqrtf((s0.x + s1.x) * (1.f / HD) + 1e-6f);
            rfac[i][1] = rsqrtf((s0.y + s1.y) * (1.f / HD) + 1e-6f);
            rfac[i][2] = rsqrtf((s0.z + s1.z) * (1.f / HD) + 1e-6f);
            rfac[i][3] = rsqrtf((s0.w + s1.w) * (1.f / HD) + 1e-6f);
        }
        const float* scale = mq ? k_scale : q_scale;
        float sgn = (l15 & 1) ? 1.f : -1.f;
        u16* obase = qkbf + (size_t)(mq * NH + h) * L_SEQ * HD;
        #pragma unroll
        for (int j = 0; j < 4; j++) {
            int d = wn * 64 + j * 16 + l15;
            float sd = scale[d];
            #pragma unroll
            for (int i = 0; i < 2; i++)
                #pragma unroll
                for (int r = 0; r < 4; r++) {
                    int row = bm + wm * 32 + i * 16 + quad * 4 + r;
                    float t = acc[i][j][r] * rfac[i][r] * sd;
                    float tp = __shfl_xor(t, 1);
                    float2 cs = pe2[row * 64 + (d >> 1)];
                    float o = fmaf(cs.x, t, sgn * cs.y * tp);
                    obase[(size_t)row * HD + d] = f2bf(o);
                }
        }
    }
}

// ---------------------------------------------------------------------------
// bf16 MFMA flash attention, FIXED-max softmax (M = 64 log2-units; safe since
// RMSNorm bounds |q|=|k|=sqrt(128) -> |s|*sc <= 16.4 log2; fp is scale-free so
// the offset costs no precision). No online rescale, no per-iter shfls.
// Single-buffered (R3 form): 41 KB LDS -> 3 blocks/CU = 12 waves/CU; the
// dbuf variant (R5) cost a block of occupancy and regressed ~24 us.
// XCD-grouped dispatch: bid&7 = XCD owns 3 heads (KV L2-resident).
// ---------------------------------------------------------------------------
__global__ __launch_bounds__(256) void attn_mfma_kernel(
    const u16* __restrict__ qk_bf, const u16* __restrict__ vT, u16* __restrict__ Og)
{
    __shared__ __align__(16) u16 k_s[64 * 128];    // 16 KB, [kv][d] 16-chunk swizzled
    __shared__ __align__(16) u16 v_s[128 * 64];    // 16 KB, [d][kv] 8-chunk swizzled
    __shared__ __align__(16) u16 p_s[4][16 * 72];  // 9 KB per-wave P

    int bid = blockIdx.x;
    int loc = bid >> 3;
    int h = (bid & 7) * 3 + (loc >> 5);
    int q0 = (loc & 31) * 64;
    int tid = threadIdx.x;
    int wave = tid >> 6, lane = tid & 63;
    int quad = lane >> 4, l15 = lane & 15;
    const u16* qb = qk_bf + (size_t)h * L_SEQ * HD;
    const u16* kb = qk_bf + (size_t)(NH + h) * L_SEQ * HD;
    const u16* vTh = vT + (size_t)h * HD * L_SEQ;

    bf16x8 aq[4];
    {
        const u16* qr = qb + (size_t)(q0 + wave * 16 + l15) * HD + quad * 8;
        #pragma unroll
        for (int ks = 0; ks < 4; ks++) aq[ks] = *(const bf16x8*)(qr + ks * 32);
    }

    f32x4 o_acc[8];
    #pragma unroll
    for (int n = 0; n < 8; n++) o_acc[n] = (f32x4){0.f, 0.f, 0.f, 0.f};
    float lsum[4] = {0.f, 0.f, 0.f, 0.f};
    const float sc = 0.08838834764831845f * 1.4426950408889634f;  // /sqrt(128)*log2e
    const float MB = 64.0f;                                       // fixed max, log2 units

    const u16* gk[4];
    #pragma unroll
    for (int e = 0; e < 4; e++) {
        int r = wave * 16 + e * 4 + (lane >> 4);
        int g = l15 ^ (r & 15);
        gk[e] = kb + (size_t)r * HD + g * 8;
    }
    const u16* gv[4];
    #pragma unroll
    for (int e = 0; e < 4; e++) {
        int d = wave * 32 + e * 8 + (lane >> 3);
        gv[e] = vTh + (size_t)d * L_SEQ + (lane & 7) * 8;
    }
    int vco[2];
    #pragma unroll
    for (int ks = 0; ks < 2; ks++) vco[ks] = ((ks * 4 + quad) ^ (l15 & 7)) * 8;

    for (int kv0 = 0; kv0 < L_SEQ; kv0 += 64) {
        __syncthreads();
        #pragma unroll
        for (int e = 0; e < 4; e++) {
            GLOBAL_TO_LDS16(gk[e] + (size_t)kv0 * HD, &k_s[(wave * 16 + e * 4) * 128]);
            GLOBAL_TO_LDS16(gv[e] + kv0, &v_s[(wave * 32 + e * 8) * 64]);
        }
        __syncthreads();

        // S = Q K^T
        f32x4 sacc[4];
        #pragma unroll
        for (int j = 0; j < 4; j++) sacc[j] = (f32x4){0.f, 0.f, 0.f, 0.f};
        #pragma unroll
        for (int ks = 0; ks < 4; ks++) {
            #pragma unroll
            for (int j = 0; j < 4; j++) {
                int n = j * 16 + l15;
                int slot = (ks * 4 + quad) ^ (n & 15);
                bf16x8 bk = *(const bf16x8*)&k_s[n * 128 + slot * 8];
                sacc[j] = __builtin_amdgcn_mfma_f32_16x16x32_bf16(aq[ks], bk, sacc[j], 0, 0, 0);
            }
        }

        // p = exp2(s*sc - MB); accumulate row sums; write P to LDS
        #pragma unroll
        for (int j = 0; j < 4; j++)
            #pragma unroll
            for (int r = 0; r < 4; r++) {
                float p = exp2f(fmaf(sacc[j][r], sc, -MB));
                sacc[j][r] = p;
                lsum[r] += p;
                p_s[wave][(quad * 4 + r) * 72 + j * 16 + l15] = f2bf(p);
            }
        bf16x8 ap[2];
        #pragma unroll
        for (int ks = 0; ks < 2; ks++)
            ap[ks] = *(const bf16x8*)&p_s[wave][l15 * 72 + ks * 32 + quad * 8];

        // O += P V  (no rescale — fixed max)
        #pragma unroll
        for (int ks = 0; ks < 2; ks++) {
            #pragma unroll
            for (int n = 0; n < 8; n++) {
                bf16x8 bv = *(const bf16x8*)&v_s[(n * 16 + l15) * 64 + vco[ks]];
                o_acc[n] = __builtin_amdgcn_mfma_f32_16x16x32_bf16(ap[ks], bv, o_acc[n], 0, 0, 0);
            }
        }
    }

    // single end-of-loop row-sum reduction across the 16-lane groups
    #pragma unroll
    for (int r = 0; r < 4; r++) {
        #pragma unroll
        for (int mm = 8; mm; mm >>= 1) lsum[r] += __shfl_xor(lsum[r], mm);
    }

    #pragma unroll
    for (int r = 0; r < 4; r++) {
        float inv = 1.f / lsum[r];
        int row = q0 + wave * 16 + quad * 4 + r;
        u16* orow = Og + (size_t)row * KE + h * HD;
        #pragma unroll
        for (int n = 0; n < 8; n++)
            orow[n * 16 + l15] = f2bf(o_acc[n][r] * inv);
    }
}

// ---------------------------------------------------------------------------
extern "C" void kernel_launch(void* const* d_in, const int* in_sizes, int n_in,
                              void* d_out, int out_size, void* d_ws, size_t ws_size,
                              hipStream_t stream)
{
    const float* x         = (const float*)d_in[0];
    const float* pe        = (const float*)d_in[1];
    const float* qkv_w     = (const float*)d_in[2];
    const float* qkv_b     = (const float*)d_in[3];
    const float* proj_w    = (const float*)d_in[4];
    const float* proj_b    = (const float*)d_in[5];
    const float* qkv_down  = (const float*)d_in[6];
    const float* qkv_up    = (const float*)d_in[7];
    const float* proj_down = (const float*)d_in[8];
    const float* proj_up   = (const float*)d_in[9];
    const float* q_scale   = (const float*)d_in[10];
    const float* k_scale   = (const float*)d_in[11];
    float* out = (float*)d_out;

    char* w = (char*)d_ws;
    u16*   qk_bf  = (u16*)w;    w += (size_t)2 * NH * L_SEQ * HD * 2;  // 25.2 MB
    u16*   vT_bf  = (u16*)w;    w += (size_t)NH * HD * L_SEQ * 2;      // 12.6 MB
    u16*   x_ext  = (u16*)w;    w += (size_t)L_SEQ * KE * 2;           // 12.8 MB
    u16*   wq_ext = (u16*)w;    w += (size_t)N_QKV * KE * 2;           // 57.8 MB
    u16*   wp_ext = (u16*)w;    w += (size_t)DIM * KE * 2;             // 19.3 MB
    u16*   o_ext  = (u16*)w;    w += (size_t)L_SEQ * KE * 2;           // 12.8 MB
    float2* pe2   = (float2*)w;

    // 6 launches (was 10): prep(pe+2x pack_w) | lora+pack_x | gemm qkv |
    // attn | lora+pack_t | gemm proj
    prep_kernel<<<N_QKV + DIM + 512, 256, 0, stream>>>(
        qkv_w, qkv_up, proj_w, proj_up, pe, wq_ext, wp_ext, pe2);
    lora_pack_x_kernel<<<L_SEQ, 256, 0, stream>>>(x, qkv_down, x_ext);

    gemm_mfma_kernel<1><<<(N_QKV / 128) * (L_SEQ / 128), 512, 0, stream>>>(
        x_ext, wq_ext, qkv_b, nullptr, qk_bf, vT_bf, pe2, q_scale, k_scale,
        L_SEQ, N_QKV, KE);
    attn_mfma_kernel<<<(L_SEQ / 64) * NH, 256, 0, stream>>>(qk_bf, vT_bf, o_ext);
    lora_pack_t_kernel<<<L_SEQ, 256, 0, stream>>>(o_ext, proj_down);
    gemm_mfma_kernel<0><<<(DIM / 128) * (L_SEQ / 128), 512, 0, stream>>>(
        o_ext, wp_ext, proj_b, out, nullptr, nullptr, nullptr, nullptr, nullptr,
        L_SEQ, DIM, KE);
}